// Round 9
// baseline (216.606 us; speedup 1.0000x reference)
//
#include <hip/hip_runtime.h>
#include <math.h>
#include <float.h>

typedef unsigned long long u64;
typedef unsigned u32;

#define NT 1024        // fallback + k2/k4 block size
#define NW 16
#define NT1 256        // streaming block size
#define SL 8           // slices per row (k1, k3)
#define NB 8192        // 13-bit value buckets (count hist)
#define BSH 19         // key >> BSH = count bucket
#define NBM 4096       // 12-bit mass buckets (key >> 20)
#define CAP 2048       // candidate capacity per row
#define SUBCAP 768     // sublist capacity (bucket kb / bucket gp)
#define TOPN 5
#define SCALE_D 17592186044416.0  // 2^44 fixed-point scale
#define NEG_BIG -3.0e38f          // finite stand-in for -inf on output

struct RowCtl { u32 kb; u32 cnt0; u32 maxKey; u32 rin; u32 bail; u32 pad[27]; };  // 128 B

__device__ __forceinline__ u32 key_of(float f){
  u32 u = __float_as_uint(f);
  return (u & 0x80000000u) ? ~u : (u | 0x80000000u);
}
__device__ __forceinline__ float key_to_float(u32 k){
  u32 u = (k & 0x80000000u) ? (k & 0x7FFFFFFFu) : ~k;
  return __uint_as_float(u);
}
__device__ __forceinline__ u64 quantMass(float l, float m){
  float ef = expf(l - m);                 // <= 1
  return (u64)((double)ef * SCALE_D + 0.5);
}

struct Top5 { float v[TOPN]; int ix[TOPN]; };
__device__ __forceinline__ void t5_init(Top5& t){
  for (int j=0;j<TOPN;j++){ t.v[j] = -INFINITY; t.ix[j] = 0x7FFFFFFF; }
}
__device__ __forceinline__ void t5_insert(Top5& t, float nv, int ni){
  for (int j=0;j<TOPN;j++){
    if (nv > t.v[j] || (nv == t.v[j] && ni < t.ix[j])){
      for (int s=TOPN-1;s>j;s--){ t.v[s]=t.v[s-1]; t.ix[s]=t.ix[s-1]; }
      t.v[j]=nv; t.ix[j]=ni;
      return;
    }
  }
}

// exclusive prefix sum over arr[0..n), arr[n]=total. 1024 threads.
__device__ void scan_excl(u64* arr, int n, u64* wsum){
  const int tid = threadIdx.x, lane = tid & 63, w = tid >> 6;
  __syncthreads();
  const int chunk = (n + NT - 1) / NT;
  const int base = tid * chunk;
  u64 local = 0;
  for (int j=0;j<chunk;j++){ int i=base+j; if (i<n) local += arr[i]; }
  u64 inc = local;
  for (int off=1; off<64; off<<=1){
    u64 up = __shfl_up(inc, off, 64);
    if (lane >= off) inc += up;
  }
  if (lane == 63) wsum[w] = inc;
  __syncthreads();
  if (tid == 0){
    u64 acc = 0;
    for (int i=0;i<NW;i++){ u64 v = wsum[i]; wsum[i] = acc; acc += v; }
    arr[n] = acc;
  }
  __syncthreads();
  u64 run = wsum[w] + (inc - local);
  for (int j=0;j<chunk;j++){ int i=base+j; if (i<n){ u64 v=arr[i]; arr[i]=run; run += v; } }
  __syncthreads();
}

// ======================= pipeline kernels =======================

__global__ void k0_zero(u32* __restrict__ hist, u32* __restrict__ ctlw, int Bn){
  size_t n = (size_t)Bn * NB;
  size_t stride = (size_t)gridDim.x * blockDim.x;
  for (size_t i = (size_t)blockIdx.x*blockDim.x + threadIdx.x; i < n; i += stride) hist[i] = 0;
  size_t nc = (size_t)Bn * (sizeof(RowCtl)/4);
  for (size_t i = (size_t)blockIdx.x*blockDim.x + threadIdx.x; i < nc; i += stride) ctlw[i] = 0;
}

__global__ __launch_bounds__(NT1) void k1_hist(const float* __restrict__ L,
        const float* __restrict__ temp, u32* __restrict__ hist, RowCtl* __restrict__ ctl,
        int Bn, int Vn){
  __shared__ u32 lh[NB];
  const int b = blockIdx.y, s = blockIdx.x, tid = threadIdx.x;
  for (int j=tid;j<NB;j+=NT1) lh[j]=0;
  const float tr = temp[b]; const float tEff = (tr < 1e-5f) ? 1.0f : tr;
  const float* Lr = L + (size_t)b*Vn;
  const int chunk = (Vn + SL-1)/SL;
  const int i0 = s*chunk, i1 = min(i0+chunk, Vn);
  __syncthreads();
  const int nv = (i1 - i0) / 4;
  const float4* L4 = (const float4*)(Lr + i0);
  u32 mk = 0;
  for (int v=tid; v<nv; v+=NT1){
    float4 x = L4[v];
    #pragma unroll
    for (int e=0;e<4;e++){
      float l = (&x.x)[e] / tEff;
      u32 k = key_of(l);
      atomicAdd(&lh[k>>BSH], 1u);
      mk = max(mk, k);
    }
  }
  for (int i=i0+nv*4+tid; i<i1; i+=NT1){
    float l = Lr[i]/tEff;
    u32 k = key_of(l);
    atomicAdd(&lh[k>>BSH], 1u);
    mk = max(mk, k);
  }
  for (int off=32; off; off>>=1){ u32 o=__shfl_xor(mk,off,64); mk=max(mk,o); }
  if ((tid&63)==0) atomicMax(&ctl[b].maxKey, mk);
  __syncthreads();
  u32* Hr = hist + (size_t)b*NB;
  for (int j=tid;j<NB;j+=NT1){ u32 c = lh[j]; if (c) atomicAdd(&Hr[j], c); }
}

__global__ __launch_bounds__(NT) void k2_kb(const int* __restrict__ top_k,
        const u32* __restrict__ hist, RowCtl* __restrict__ ctl, int Bn, int Vn){
  __shared__ u32 sh[NB+1];
  __shared__ u32 wsum[NW];
  __shared__ int s_g;
  __shared__ u32 s_base;
  const int b = blockIdx.x, tid = threadIdx.x, lane = tid&63, w = tid>>6;
  const u32* Hr = hist + (size_t)b*NB;
  for (int j=tid;j<NB;j+=NT) sh[j] = Hr[j];
  __syncthreads();
  const int chunk = NB/NT;  // 8
  u32 local=0;
  for (int j=0;j<chunk;j++) local += sh[tid*chunk+j];
  u32 inc = local;
  for (int off=1;off<64;off<<=1){ u32 up=__shfl_up(inc,off,64); if (lane>=off) inc+=up; }
  if (lane==63) wsum[w]=inc;
  __syncthreads();
  if (tid==0){ u32 acc=0; for(int i=0;i<NW;i++){u32 v=wsum[i]; wsum[i]=acc; acc+=v;} sh[NB]=acc; }
  __syncthreads();
  u32 run = wsum[w] + (inc - local);
  for (int j=0;j<chunk;j++){ int i2=tid*chunk+j; u32 v=sh[i2]; sh[i2]=run; run+=v; }
  __syncthreads();
  int kk = top_k[b]; if (kk<1) kk=1; if (kk>Vn) kk=Vn;
  const u32 rank = (u32)(Vn - kk);
  for (int j=tid;j<NB;j+=NT) if (sh[j] <= rank && rank < sh[j+1]){ s_g = j; s_base = sh[j]; }
  __syncthreads();
  if (tid==0){ ctl[b].kb = (u32)s_g; ctl[b].rin = rank - s_base; }
}

__global__ __launch_bounds__(NT1) void k3_collect(const float* __restrict__ L,
        const float* __restrict__ temp, u64* __restrict__ cand, RowCtl* __restrict__ ctl,
        int Bn, int Vn){
  const int b = blockIdx.y, s = blockIdx.x, tid = threadIdx.x;
  const float tr = temp[b]; const float tEff = (tr<1e-5f)?1.0f:tr;
  const u32 kbMinKey = ctl[b].kb << BSH;
  const float* Lr = L + (size_t)b*Vn;
  u64* Cr = cand + (size_t)b*CAP;
  const int chunk = (Vn + SL-1)/SL;
  const int i0 = s*chunk, i1 = min(i0+chunk, Vn);
  const int nv = (i1 - i0) / 4;
  const float4* L4 = (const float4*)(Lr + i0);
  const int lane = tid & 63;
  for (int v=tid; v<nv; v+=NT1){
    float4 x = L4[v];
    #pragma unroll
    for (int e=0;e<4;e++){
      float l = (&x.x)[e] / tEff;
      u32 k = key_of(l);
      bool pred = (k >= kbMinKey);
      u64 mk = __ballot(pred);
      if (mk){
        int leader = __ffsll((long long)mk) - 1;
        u32 base = 0;
        if (lane == leader) base = atomicAdd(&ctl[b].cnt0, (u32)__popcll(mk));
        base = __shfl(base, leader, 64);
        if (pred){
          u32 p = base + (u32)__popcll(mk & ((1ull<<lane)-1ull));
          if (p < CAP) Cr[p] = ((u64)k<<32) | (u64)(u32)(i0 + v*4 + e);
        }
      }
    }
  }
  for (int i=i0+nv*4+tid; i<i1; i+=NT1){
    float l = Lr[i]/tEff;
    u32 k = key_of(l);
    if (k >= kbMinKey){
      u32 p = atomicAdd(&ctl[b].cnt0, 1u);
      if (p < CAP) Cr[p] = ((u64)k<<32) | (u64)(u32)i;
    }
  }
}

// k4 v5: minimal-serial-step solve. ~16 barriers total.
// thr via brute-force pair-rank in bucket kb; top-p via 4096-bucket mass scan
// + brute-force inside the crossing bucket. No sort, no descents.
__global__ __launch_bounds__(NT) void k4_solve(const float* __restrict__ L,
        const float* __restrict__ temp, const int* __restrict__ top_k,
        const float* __restrict__ top_p, const float* __restrict__ qn,
        const u64* __restrict__ cand, RowCtl* __restrict__ ctl,
        float* __restrict__ out, int Bn, int Vn){
  __shared__ u64 Hm[NBM+1];       // 32.8 KB
  __shared__ u64 sub[SUBCAP];     // 6 KB
  __shared__ u64 msub[SUBCAP];    // 6 KB
  __shared__ u64 wsum[NW];
  __shared__ int s_cnt;
  __shared__ int s_bail;
  __shared__ u32 s_thr;
  __shared__ int s_gp;
  __shared__ Top5 s_wt5[NW];
  __shared__ double s_wr[NW];
  __shared__ int s_wri[NW];
  __shared__ int s_wg[NW];
  __shared__ u64 s_ms[NW];
  __shared__ u64 s_pb[NW];

  const int b = blockIdx.x, tid = threadIdx.x, lane = tid&63, w = tid>>6;
  const u32 n0raw = ctl[b].cnt0;
  if (n0raw == 0 || n0raw > CAP) return;      // k5 row-fallback
  const int n0 = (int)n0raw;
  const float tr = temp[b]; const float tEff = (tr<1e-5f)?1.0f:tr;
  const float* Lr = L + (size_t)b*Vn;
  const float* Qr = qn + (size_t)b*Vn;
  const u64* Cr = cand + (size_t)b*CAP;
  const u32 kb = ctl[b].kb;
  const u32 rin = ctl[b].rin;
  const u32 mKey = ctl[b].maxKey;
  const float m = key_to_float(mKey);

  // ---- load own candidates (2 per thread, coalesced) ----
  const bool v0 = (tid < n0), v1 = (tid + NT < n0);
  const u64 o0 = v0 ? Cr[tid] : ~0ull;
  const u64 o1 = v1 ? Cr[tid+NT] : ~0ull;
  const u32 k0 = (u32)(o0>>32), k1v = (u32)(o1>>32);
  if (tid==0){ s_cnt = 0; s_bail = 0; }
  __syncthreads();

  // ---- step 1: bucket-kb sublist ----
  const bool in0 = v0 && ((k0>>BSH) == kb);
  const bool in1 = v1 && ((k1v>>BSH) == kb);
  if (in0){ int p = atomicAdd(&s_cnt,1); if (p<SUBCAP) sub[p]=o0; else s_bail=1; }
  if (in1){ int p = atomicAdd(&s_cnt,1); if (p<SUBCAP) sub[p]=o1; else s_bail=1; }
  __syncthreads();
  const int nkb = min(s_cnt, SUBCAP);
  if (s_bail){ if (tid==0) ctl[b].bail = 1; return; }

  // ---- step 2: brute-force pair-rank in bucket kb -> exact k-th largest key ----
  // barrier-free broadcast loop; rank of own pair among kb pairs
  u32 r0=0, r1=0;
  for (int j=0;j<nkb;j++){
    u64 pj = sub[j];                          // same addr all lanes -> broadcast
    r0 += (in0 && pj < o0);
    r1 += (in1 && pj < o1);
  }
  if (in0 && r0 == rin) s_thr = k0;
  if (in1 && r1 == rin) s_thr = k1v;
  __syncthreads();
  const u32 thrKey = s_thr;

  // ---- step 3: survivor masses + 4096-bucket mass histogram ----
  const u64 m0 = (v0 && k0  >= thrKey) ? quantMass(key_to_float(k0),  m) : 0ull;
  const u64 m1 = (v1 && k1v >= thrKey) ? quantMass(key_to_float(k1v), m) : 0ull;
  for (int i=tid;i<NBM+1;i+=NT) Hm[i] = 0;
  __syncthreads();
  if (m0) atomicAdd(&Hm[k0 >>20], m0);
  if (m1) atomicAdd(&Hm[k1v>>20], m1);
  scan_excl(Hm, NBM, wsum);                   // leading barrier covers the adds
  const u64 T = Hm[NBM];
  const float cf = 1.0f - top_p[b];           // ref: f32 (1.0 - top_p)
  u64 Q = (u64)((double)cf * (double)T);
  if (Q >= T) Q = T - 1;                      // ref: p_mask[:, -1] = False

  // ---- step 4: crossing bucket gp ----
  for (int g=tid; g<NBM; g+=NT)
    if (Hm[g] <= Q && Q < Hm[g+1]) s_gp = g;
  __syncthreads();
  const int gp = s_gp;
  const u64 Pgp = Hm[gp];
  if (tid==0) s_cnt = 0;
  __syncthreads();

  // ---- step 5: bucket-gp sublist (pairs + masses) ----
  const bool g0in = (m0 != 0) && ((k0 >>20) == (u32)gp);
  const bool g1in = (m1 != 0) && ((k1v>>20) == (u32)gp);
  if (g0in){ int p = atomicAdd(&s_cnt,1); if (p<SUBCAP){ sub[p]=o0; msub[p]=m0; } else s_bail=1; }
  if (g1in){ int p = atomicAdd(&s_cnt,1); if (p<SUBCAP){ sub[p]=o1; msub[p]=m1; } else s_bail=1; }
  __syncthreads();
  const int ngp = min(s_cnt, SUBCAP);
  if (s_bail){ if (tid==0) ctl[b].bail = 1; return; }

  // ---- step 6: per-element masked decision (brute-force within gp) ----
  u64 c0=0, c1=0;
  for (int j=0;j<ngp;j++){
    u64 pj = sub[j]; u64 mj = msub[j];        // broadcasts
    if (g0in && pj < o0) c0 += mj;
    if (g1in && pj < o1) c1 += mj;
  }
  const bool masked0 = (m0!=0) && ( ((k0 >>20) < (u32)gp) || (g0in && (Pgp + c0 + m0) <= Q) );
  const bool masked1 = (m1!=0) && ( ((k1v>>20) < (u32)gp) || (g1in && (Pgp + c1 + m1) <= Q) );
  const bool sv0 = (m0!=0) && !masked0;
  const bool sv1 = (m1!=0) && !masked1;

  // ---- step 7: reductions (masked mass, min surviving pair) + epilogue ----
  u64 mm = (masked0?m0:0) + (masked1?m1:0);
  u64 pb = ~0ull;
  if (sv0) pb = o0;
  if (sv1 && o1 < pb) pb = o1;
  float q0 = sv0 ? Qr[(u32)o0] : 1.0f;
  float q1 = sv1 ? Qr[(u32)o1] : 1.0f;

  Top5 t5; t5_init(t5);
  double br = -1.0; int bri = 0x7FFFFFFF; int gmin = 0x7FFFFFFF;
  if (sv0){
    float l = key_to_float(k0); int idx = (int)(u32)o0;
    double ratio = (double)expf(l - m) / (double)(-logf(q0));
    if (ratio > br || (ratio == br && idx < bri)){ br = ratio; bri = idx; }
    if (k0 == mKey && idx < gmin) gmin = idx;
    t5_insert(t5, l, idx);
  }
  if (sv1){
    float l = key_to_float(k1v); int idx = (int)(u32)o1;
    double ratio = (double)expf(l - m) / (double)(-logf(q1));
    if (ratio > br || (ratio == br && idx < bri)){ br = ratio; bri = idx; }
    if (k1v == mKey && idx < gmin) gmin = idx;
    t5_insert(t5, l, idx);
  }
  for (int off=1; off<64; off<<=1){
    Top5 o;
    for (int j=0;j<TOPN;j++){ o.v[j]=__shfl_xor(t5.v[j],off,64); o.ix[j]=__shfl_xor(t5.ix[j],off,64); }
    for (int j=0;j<TOPN;j++) t5_insert(t5, o.v[j], o.ix[j]);
    double orr = __shfl_xor(br, off, 64); int ori = __shfl_xor(bri, off, 64);
    if (orr > br || (orr == br && ori < bri)){ br = orr; bri = ori; }
    int og = __shfl_xor(gmin, off, 64); if (og < gmin) gmin = og;
    mm += __shfl_xor(mm, off, 64);
    u64 op = __shfl_xor(pb, off, 64); if (op < pb) pb = op;
  }
  if (lane==0){ s_wt5[w]=t5; s_wr[w]=br; s_wri[w]=bri; s_wg[w]=gmin; s_ms[w]=mm; s_pb[w]=pb; }
  __syncthreads();
  if (tid==0){
    Top5 f = s_wt5[0];
    double fr = s_wr[0]; int fri = s_wri[0]; int fg = s_wg[0];
    u64 fms = s_ms[0]; u64 fpb = s_pb[0];
    for (int wi=1; wi<NW; wi++){
      for (int j=0;j<TOPN;j++) t5_insert(f, s_wt5[wi].v[j], s_wt5[wi].ix[j]);
      if (s_wr[wi] > fr || (s_wr[wi]==fr && s_wri[wi]<fri)){ fr=s_wr[wi]; fri=s_wri[wi]; }
      if (s_wg[wi] < fg) fg = s_wg[wi];
      fms += s_ms[wi];
      if (s_pb[wi] < fpb) fpb = s_pb[wi];
    }
    const u64 S2 = T - fms;
    // -inf fill: 5 smallest non-surviving vocab indices live in [0,16) whenever they matter
    int filled = 0;
    for (int i=0; i<16 && i<Vn && filled<TOPN; i++){
      float l = Lr[i]/tEff;
      u64 pr = ((u64)key_of(l)<<32) | (u64)(u32)i;
      if (pr < fpb){ t5_insert(f, -INFINITY, i); filled++; }
    }
    double lS = log((double)S2 / SCALE_D);
    int sampled = (tr < 1e-5f) ? fg : fri;
    out[b] = (float)sampled;
    for (int j=0;j<TOPN;j++){
      float lv = f.v[j];
      float lp = (lv == -INFINITY) ? NEG_BIG : (float)((double)lv - (double)m - lS);
      out[Bn + b*TOPN + j] = lp;
      out[Bn + Bn*TOPN + b*TOPN + j] = (float)f.ix[j];
    }
  }
}

// ======================= per-row full fallback (round-2 algorithm, verified) =======================

__device__ void find_cross(const u64* arr, int n, u64 target, int* s_fh, u64* s_fb){
  const int tid = threadIdx.x;
  const int chunk = (n + NT - 1) / NT;
  const int base = tid * chunk;
  for (int j=0;j<chunk;j++){
    int i = base + j;
    if (i < n && arr[i] <= target && target < arr[i+1]){ *s_fh = i; *s_fb = arr[i]; }
  }
  __syncthreads();
}

__device__ void fallback_row(int b, const float* logits, const float* temperature,
                             const int* top_k, const float* top_p, const float* qnoise,
                             float* out, int Bn, int Vn){
  __shared__ u64 s_hist[4097];
  __shared__ u64 s_wsum[NW];
  __shared__ int s_fh;
  __shared__ u64 s_fb;
  __shared__ float s_fm[NW];
  __shared__ float s_m;
  __shared__ int s_lastMax;
  __shared__ int s_eqcnt;
  __shared__ int s_eqlist[1024];
  __shared__ int s_sel;
  __shared__ Top5 s_wt5[NW];
  __shared__ double s_wr[NW];
  __shared__ int s_wri[NW];
  __shared__ int s_wg[NW];
  __shared__ u64 s_ws2[NW];

  const int tid = threadIdx.x, lane = tid & 63, w = tid >> 6;
  const float* L  = logits + (size_t)b * Vn;
  const float* Qr = qnoise + (size_t)b * Vn;
  const float tRaw = temperature[b];
  const float tEff = (tRaw < 1e-5f) ? 1.0f : tRaw;

  for (int i=tid;i<4097;i+=NT) s_hist[i] = 0;
  if (tid==0){ s_lastMax = -1; s_eqcnt = 0; }
  __syncthreads();
  float lm = -INFINITY;
  for (int i=tid;i<Vn;i+=NT){
    float l = L[i] / tEff;
    u32 k = key_of(l);
    atomicAdd(&s_hist[k>>20], 1ull);
    lm = fmaxf(lm, l);
  }
  for (int off=32; off; off>>=1) lm = fmaxf(lm, __shfl_xor(lm, off, 64));
  if (lane==0) s_fm[w] = lm;
  scan_excl(s_hist, 4096, s_wsum);
  if (tid==0){ float mm=-INFINITY; for (int i=0;i<NW;i++) mm=fmaxf(mm,s_fm[i]); s_m=mm; }
  __syncthreads();
  const float m = s_m;

  int kk = top_k[b]; if (kk < 1) kk = 1; if (kk > Vn) kk = Vn;
  u64 r = (u64)(Vn - kk);
  find_cross(s_hist, 4096, r, &s_fh, &s_fb);
  const int kb0 = s_fh; r -= s_fb;
  __syncthreads();

  for (int i=tid;i<4097;i+=NT) s_hist[i]=0;
  __syncthreads();
  for (int i=tid;i<Vn;i+=NT){
    float l = L[i]/tEff; u32 k = key_of(l);
    if ((int)(k>>20) == kb0) atomicAdd(&s_hist[(k>>8)&0xFFFu], 1ull);
  }
  scan_excl(s_hist, 4096, s_wsum);
  find_cross(s_hist, 4096, r, &s_fh, &s_fb);
  const int kb1 = s_fh; r -= s_fb;
  __syncthreads();

  const u32 ktop24 = ((u32)kb0<<12) | (u32)kb1;
  for (int i=tid;i<4097;i+=NT) s_hist[i]=0;
  __syncthreads();
  for (int i=tid;i<Vn;i+=NT){
    float l = L[i]/tEff; u32 k = key_of(l);
    if ((k>>8) == ktop24) atomicAdd(&s_hist[k & 0xFFu], 1ull);
  }
  scan_excl(s_hist, 256, s_wsum);
  find_cross(s_hist, 256, r, &s_fh, &s_fb);
  const u32 thrKey = (ktop24<<8) | (u32)s_fh;
  const float thr = key_to_float(thrKey);
  __syncthreads();

  for (int i=tid;i<4097;i+=NT) s_hist[i]=0;
  __syncthreads();
  for (int i=tid;i<Vn;i+=NT){
    float l = L[i]/tEff;
    if (l >= thr){
      u32 k = key_of(l);
      double sd = exp((double)l - (double)m);
      u64 qv = (u64)(sd * SCALE_D + 0.5);
      atomicAdd(&s_hist[k>>20], qv);
      if (l == m) atomicMax(&s_lastMax, i);
    }
  }
  scan_excl(s_hist, 4096, s_wsum);
  const u64 T = s_hist[4096];
  const float cf = 1.0f - top_p[b];
  const double qtd = (double)cf * (double)T;
  u64 Qfix = (qtd >= (double)T) ? T : (u64)qtd;
  const bool allmask = (Qfix >= T);

  u32 vKey = 0xFFFFFFFFu;
  int idxStar = 0x7FFFFFFF;

  if (!allmask){
    find_cross(s_hist, 4096, Qfix, &s_fh, &s_fb);
    const int g0 = s_fh;
    u64 Qrem = Qfix - s_fb;
    __syncthreads();

    for (int i=tid;i<4097;i+=NT) s_hist[i]=0;
    __syncthreads();
    for (int i=tid;i<Vn;i+=NT){
      float l = L[i]/tEff;
      if (l >= thr){
        u32 k = key_of(l);
        if ((int)(k>>20) == g0){
          double sd = exp((double)l - (double)m);
          atomicAdd(&s_hist[(k>>8)&0xFFFu], (u64)(sd*SCALE_D+0.5));
        }
      }
    }
    scan_excl(s_hist, 4096, s_wsum);
    find_cross(s_hist, 4096, Qrem, &s_fh, &s_fb);
    const int g1 = s_fh; Qrem -= s_fb;
    __syncthreads();

    const u32 ptop24 = ((u32)g0<<12)|(u32)g1;
    for (int i=tid;i<4097;i+=NT) s_hist[i]=0;
    __syncthreads();
    for (int i=tid;i<Vn;i+=NT){
      float l = L[i]/tEff;
      if (l >= thr){
        u32 k = key_of(l);
        if ((k>>8) == ptop24){
          double sd = exp((double)l - (double)m);
          atomicAdd(&s_hist[k & 0xFFu], (u64)(sd*SCALE_D+0.5));
        }
      }
    }
    scan_excl(s_hist, 256, s_wsum);
    find_cross(s_hist, 256, Qrem, &s_fh, &s_fb);
    const int g2 = s_fh;
    const u64 base2 = s_fb;
    const u64 nextPref = s_hist[g2+1];
    Qrem -= base2;
    vKey = (ptop24<<8) | (u32)g2;
    const float vStar = key_to_float(vKey);
    const double sv = exp((double)vStar - (double)m);
    const u64 qstar = (u64)(sv*SCALE_D+0.5);
    u64 nstar = (qstar > 0) ? (nextPref - base2) / qstar : 1ull;
    if (nstar < 1) nstar = 1;
    u64 tmask = (qstar > 0) ? (Qrem / qstar) : 0ull;
    if (tmask >= nstar) tmask = nstar - 1;
    idxStar = -1;
    __syncthreads();
    if (tmask >= 1){
      for (int i=tid;i<Vn;i+=NT){
        float l = L[i]/tEff;
        if (key_of(l) == vKey){
          int p = atomicAdd(&s_eqcnt, 1);
          if (p < 1024) s_eqlist[p] = i;
        }
      }
      __syncthreads();
      if (tid == 0){
        int n_ = s_eqcnt; if (n_ > 1024) n_ = 1024;
        for (int a=1;a<n_;a++){
          int key0 = s_eqlist[a]; int c2=a-1;
          while (c2>=0 && s_eqlist[c2]>key0){ s_eqlist[c2+1]=s_eqlist[c2]; c2--; }
          s_eqlist[c2+1]=key0;
        }
        int ti = (int)tmask - 1;
        if (ti >= n_) ti = n_-1;
        s_sel = s_eqlist[ti];
      }
      __syncthreads();
      idxStar = s_sel;
    }
  }

  const int lastMax = s_lastMax;
  Top5 t5; t5_init(t5);
  u64 s2 = 0;
  double br = -1.0; int bri = 0x7FFFFFFF;
  int gmin = 0x7FFFFFFF;
  for (int i=tid;i<Vn;i+=NT){
    float l = L[i]/tEff;
    u32 k = key_of(l);
    bool surv = (l >= thr) &&
                ((k > vKey) || (k == vKey && i > idxStar) || (i == lastMax));
    float val;
    if (surv){
      double sd = exp((double)l - (double)m);
      s2 += (u64)(sd*SCALE_D+0.5);
      float u = expf(l - m);
      float e = -logf(Qr[i]);
      double ratio = (double)u / (double)e;
      if (ratio > br || (ratio == br && i < bri)){ br = ratio; bri = i; }
      if (l == m && i < gmin) gmin = i;
      val = l;
    } else {
      val = -INFINITY;
    }
    t5_insert(t5, val, i);
  }
  for (int off=1; off<64; off<<=1){
    Top5 o;
    for (int j=0;j<TOPN;j++){ o.v[j]=__shfl_xor(t5.v[j],off,64); o.ix[j]=__shfl_xor(t5.ix[j],off,64); }
    for (int j=0;j<TOPN;j++) t5_insert(t5, o.v[j], o.ix[j]);
    double orr = __shfl_xor(br, off, 64);
    int ori = __shfl_xor(bri, off, 64);
    if (orr > br || (orr == br && ori < bri)){ br = orr; bri = ori; }
    int og = __shfl_xor(gmin, off, 64); if (og < gmin) gmin = og;
    s2 += __shfl_xor(s2, off, 64);
  }
  if (lane == 0){
    s_wt5[w] = t5; s_wr[w]=br; s_wri[w]=bri; s_wg[w]=gmin; s_ws2[w]=s2;
  }
  __syncthreads();
  if (tid == 0){
    Top5 f = s_wt5[0];
    double fr = s_wr[0]; int fri = s_wri[0]; int fg = s_wg[0];
    u64 fs2 = s_ws2[0];
    for (int wi=1; wi<NW; wi++){
      for (int j=0;j<TOPN;j++) t5_insert(f, s_wt5[wi].v[j], s_wt5[wi].ix[j]);
      if (s_wr[wi] > fr || (s_wr[wi]==fr && s_wri[wi]<fri)){ fr=s_wr[wi]; fri=s_wri[wi]; }
      if (s_wg[wi] < fg) fg = s_wg[wi];
      fs2 += s_ws2[wi];
    }
    double S2d = (double)fs2 / SCALE_D;
    double lS = log(S2d);
    int sampled = (tRaw < 1e-5f) ? fg : fri;
    out[b] = (float)sampled;
    for (int j=0;j<TOPN;j++){
      float lv = f.v[j];
      float lp = (lv == -INFINITY) ? NEG_BIG : (float)((double)lv - (double)m - lS);
      out[Bn + b*TOPN + j] = lp;
      out[Bn + Bn*TOPN + b*TOPN + j] = (float)f.ix[j];
    }
  }
}

__global__ __launch_bounds__(NT) void k5_rowfb(const float* __restrict__ logits,
        const float* __restrict__ temperature, const int* __restrict__ top_k,
        const float* __restrict__ top_p, const float* __restrict__ qnoise,
        const RowCtl* __restrict__ ctl, float* __restrict__ out, int Bn, int Vn){
  const int b = blockIdx.x;
  const u32 c = ctl[b].cnt0;
  if (c > 0 && c <= CAP && !ctl[b].bail) return;   // handled by k4
  fallback_row(b, logits, temperature, top_k, top_p, qnoise, out, Bn, Vn);
}

extern "C" __global__ void __launch_bounds__(NT)
sampler_fallback(const float* __restrict__ logits, const float* __restrict__ temperature,
                 const int* __restrict__ top_k, const float* __restrict__ top_p,
                 const float* __restrict__ qnoise, float* __restrict__ out, int Bn, int Vn){
  fallback_row(blockIdx.x, logits, temperature, top_k, top_p, qnoise, out, Bn, Vn);
}

// ======================= launch =======================

extern "C" void kernel_launch(void* const* d_in, const int* in_sizes, int n_in,
                              void* d_out, int out_size, void* d_ws, size_t ws_size,
                              hipStream_t stream)
{
  const float* logits      = (const float*)d_in[0];
  const float* temperature = (const float*)d_in[1];
  const int*   top_k       = (const int*)d_in[2];
  const float* top_p       = (const float*)d_in[3];
  const float* q           = (const float*)d_in[4];
  const int Bn = in_sizes[1];
  const int Vn = in_sizes[0] / Bn;

  const size_t offCand = (size_t)Bn * NB * 4;                 // hist u32
  const size_t offCtl  = offCand + (size_t)Bn * CAP * 8;      // cand u64
  const size_t total   = offCtl + (size_t)Bn * sizeof(RowCtl);

  if (ws_size < total){
    sampler_fallback<<<dim3(Bn), dim3(NT), 0, stream>>>(
        logits, temperature, top_k, top_p, q, (float*)d_out, Bn, Vn);
    return;
  }

  char* wsb = (char*)d_ws;
  u32*    hist = (u32*)wsb;
  u64*    cand = (u64*)(wsb + offCand);
  RowCtl* ctl  = (RowCtl*)(wsb + offCtl);

  k0_zero   <<<dim3(512),     dim3(256), 0, stream>>>(hist, (u32*)ctl, Bn);
  k1_hist   <<<dim3(SL, Bn),  dim3(NT1), 0, stream>>>(logits, temperature, hist, ctl, Bn, Vn);
  k2_kb     <<<dim3(Bn),      dim3(NT),  0, stream>>>(top_k, hist, ctl, Bn, Vn);
  k3_collect<<<dim3(SL, Bn),  dim3(NT1), 0, stream>>>(logits, temperature, cand, ctl, Bn, Vn);
  k4_solve  <<<dim3(Bn),      dim3(NT),  0, stream>>>(logits, temperature, top_k, top_p, q,
                                                      cand, ctl, (float*)d_out, Bn, Vn);
  k5_rowfb  <<<dim3(Bn),      dim3(NT),  0, stream>>>(logits, temperature, top_k, top_p, q,
                                                      ctl, (float*)d_out, Bn, Vn);
}

// Round 10
// 135.704 us; speedup vs baseline: 1.5962x; 1.5962x over previous
//
#include <hip/hip_runtime.h>
#include <math.h>
#include <float.h>

typedef unsigned long long u64;
typedef unsigned u32;

#define NT 1024        // fallback + k2 block size
#define NW 16
#define NT1 256        // streaming + k4 block size
#define SL 8           // slices per row (k1, k3)
#define NB 8192        // 13-bit value buckets (count hist)
#define BSH 19         // key >> BSH = count bucket
#define NBM 4096       // k4 histogram bins
#define CAP 2048       // candidate capacity per row
#define EPT4 8         // elements per thread in k4
#define SUB2 64        // mini-list capacity
#define TOPN 5
#define SCALE_D 17592186044416.0  // 2^44 fixed-point scale
#define NEG_BIG -3.0e38f          // finite stand-in for -inf on output

struct RowCtl { u32 kb; u32 cnt0; u32 maxKey; u32 rin; u32 bail; u32 pad[27]; };  // 128 B

__device__ __forceinline__ u32 key_of(float f){
  u32 u = __float_as_uint(f);
  return (u & 0x80000000u) ? ~u : (u | 0x80000000u);
}
__device__ __forceinline__ float key_to_float(u32 k){
  u32 u = (k & 0x80000000u) ? (k & 0x7FFFFFFFu) : ~k;
  return __uint_as_float(u);
}
__device__ __forceinline__ u64 quantMass(float l, float m){
  float ef = expf(l - m);                 // <= 1
  return (u64)((double)ef * SCALE_D + 0.5);
}

struct Top5 { float v[TOPN]; int ix[TOPN]; };
__device__ __forceinline__ void t5_init(Top5& t){
  for (int j=0;j<TOPN;j++){ t.v[j] = -INFINITY; t.ix[j] = 0x7FFFFFFF; }
}
__device__ __forceinline__ void t5_insert(Top5& t, float nv, int ni){
  for (int j=0;j<TOPN;j++){
    if (nv > t.v[j] || (nv == t.v[j] && ni < t.ix[j])){
      for (int s=TOPN-1;s>j;s--){ t.v[s]=t.v[s-1]; t.ix[s]=t.ix[s-1]; }
      t.v[j]=nv; t.ix[j]=ni;
      return;
    }
  }
}

// exclusive prefix sum over arr[0..n), arr[n]=total. 1024 threads (fallback).
__device__ void scan_excl(u64* arr, int n, u64* wsum){
  const int tid = threadIdx.x, lane = tid & 63, w = tid >> 6;
  __syncthreads();
  const int chunk = (n + NT - 1) / NT;
  const int base = tid * chunk;
  u64 local = 0;
  for (int j=0;j<chunk;j++){ int i=base+j; if (i<n) local += arr[i]; }
  u64 inc = local;
  for (int off=1; off<64; off<<=1){
    u64 up = __shfl_up(inc, off, 64);
    if (lane >= off) inc += up;
  }
  if (lane == 63) wsum[w] = inc;
  __syncthreads();
  if (tid == 0){
    u64 acc = 0;
    for (int i=0;i<NW;i++){ u64 v = wsum[i]; wsum[i] = acc; acc += v; }
    arr[n] = acc;
  }
  __syncthreads();
  u64 run = wsum[w] + (inc - local);
  for (int j=0;j<chunk;j++){ int i=base+j; if (i<n){ u64 v=arr[i]; arr[i]=run; run += v; } }
  __syncthreads();
}

// exclusive scans, 256 threads, n multiple of 256. arr[n]=total.
__device__ void scanU32_256(u32* a, int n, u32* w4){
  const int tid=threadIdx.x, lane=tid&63, w=tid>>6;
  __syncthreads();
  const int chunk = n/NT1; const int base = tid*chunk;
  u32 local=0;
  for (int j=0;j<chunk;j++) local += a[base+j];
  u32 inc=local;
  for (int off=1;off<64;off<<=1){ u32 up=__shfl_up(inc,off,64); if(lane>=off) inc+=up; }
  if (lane==63) w4[w]=inc;
  __syncthreads();
  if (tid==0){ u32 acc=0; for(int i=0;i<4;i++){u32 v=w4[i]; w4[i]=acc; acc+=v;} a[n]=acc; }
  __syncthreads();
  u32 run = w4[w] + (inc-local);
  for (int j=0;j<chunk;j++){ u32 v=a[base+j]; a[base+j]=run; run+=v; }
  __syncthreads();
}
__device__ void scanU64_256(u64* a, int n, u64* w4){
  const int tid=threadIdx.x, lane=tid&63, w=tid>>6;
  __syncthreads();
  const int chunk = n/NT1; const int base = tid*chunk;
  u64 local=0;
  for (int j=0;j<chunk;j++) local += a[base+j];
  u64 inc=local;
  for (int off=1;off<64;off<<=1){ u64 up=__shfl_up(inc,off,64); if(lane>=off) inc+=up; }
  if (lane==63) w4[w]=inc;
  __syncthreads();
  if (tid==0){ u64 acc=0; for(int i=0;i<4;i++){u64 v=w4[i]; w4[i]=acc; acc+=v;} a[n]=acc; }
  __syncthreads();
  u64 run = w4[w] + (inc-local);
  for (int j=0;j<chunk;j++){ u64 v=a[base+j]; a[base+j]=run; run+=v; }
  __syncthreads();
}

// ======================= pipeline kernels =======================

__global__ void k0_zero(u32* __restrict__ hist, u32* __restrict__ ctlw, int Bn){
  size_t n = (size_t)Bn * NB;
  size_t stride = (size_t)gridDim.x * blockDim.x;
  for (size_t i = (size_t)blockIdx.x*blockDim.x + threadIdx.x; i < n; i += stride) hist[i] = 0;
  size_t nc = (size_t)Bn * (sizeof(RowCtl)/4);
  for (size_t i = (size_t)blockIdx.x*blockDim.x + threadIdx.x; i < nc; i += stride) ctlw[i] = 0;
}

__global__ __launch_bounds__(NT1) void k1_hist(const float* __restrict__ L,
        const float* __restrict__ temp, u32* __restrict__ hist, RowCtl* __restrict__ ctl,
        int Bn, int Vn){
  __shared__ u32 lh[NB];
  const int b = blockIdx.y, s = blockIdx.x, tid = threadIdx.x;
  for (int j=tid;j<NB;j+=NT1) lh[j]=0;
  const float tr = temp[b]; const float tEff = (tr < 1e-5f) ? 1.0f : tr;
  const float* Lr = L + (size_t)b*Vn;
  const int chunk = (Vn + SL-1)/SL;
  const int i0 = s*chunk, i1 = min(i0+chunk, Vn);
  __syncthreads();
  const int nv = (i1 - i0) / 4;
  const float4* L4 = (const float4*)(Lr + i0);
  u32 mk = 0;
  for (int v=tid; v<nv; v+=NT1){
    float4 x = L4[v];
    #pragma unroll
    for (int e=0;e<4;e++){
      float l = (&x.x)[e] / tEff;
      u32 k = key_of(l);
      atomicAdd(&lh[k>>BSH], 1u);
      mk = max(mk, k);
    }
  }
  for (int i=i0+nv*4+tid; i<i1; i+=NT1){
    float l = Lr[i]/tEff;
    u32 k = key_of(l);
    atomicAdd(&lh[k>>BSH], 1u);
    mk = max(mk, k);
  }
  for (int off=32; off; off>>=1){ u32 o=__shfl_xor(mk,off,64); mk=max(mk,o); }
  if ((tid&63)==0) atomicMax(&ctl[b].maxKey, mk);
  __syncthreads();
  u32* Hr = hist + (size_t)b*NB;
  for (int j=tid;j<NB;j+=NT1){ u32 c = lh[j]; if (c) atomicAdd(&Hr[j], c); }
}

__global__ __launch_bounds__(NT) void k2_kb(const int* __restrict__ top_k,
        const u32* __restrict__ hist, RowCtl* __restrict__ ctl, int Bn, int Vn){
  __shared__ u32 sh[NB+1];
  __shared__ u32 wsum[NW];
  __shared__ int s_g;
  __shared__ u32 s_base;
  const int b = blockIdx.x, tid = threadIdx.x, lane = tid&63, w = tid>>6;
  const u32* Hr = hist + (size_t)b*NB;
  for (int j=tid;j<NB;j+=NT) sh[j] = Hr[j];
  __syncthreads();
  const int chunk = NB/NT;  // 8
  u32 local=0;
  for (int j=0;j<chunk;j++) local += sh[tid*chunk+j];
  u32 inc = local;
  for (int off=1;off<64;off<<=1){ u32 up=__shfl_up(inc,off,64); if (lane>=off) inc+=up; }
  if (lane==63) wsum[w]=inc;
  __syncthreads();
  if (tid==0){ u32 acc=0; for(int i=0;i<NW;i++){u32 v=wsum[i]; wsum[i]=acc; acc+=v;} sh[NB]=acc; }
  __syncthreads();
  u32 run = wsum[w] + (inc - local);
  for (int j=0;j<chunk;j++){ int i2=tid*chunk+j; u32 v=sh[i2]; sh[i2]=run; run+=v; }
  __syncthreads();
  int kk = top_k[b]; if (kk<1) kk=1; if (kk>Vn) kk=Vn;
  const u32 rank = (u32)(Vn - kk);
  for (int j=tid;j<NB;j+=NT) if (sh[j] <= rank && rank < sh[j+1]){ s_g = j; s_base = sh[j]; }
  __syncthreads();
  if (tid==0){ ctl[b].kb = (u32)s_g; ctl[b].rin = rank - s_base; }
}

__global__ __launch_bounds__(NT1) void k3_collect(const float* __restrict__ L,
        const float* __restrict__ temp, u64* __restrict__ cand, RowCtl* __restrict__ ctl,
        int Bn, int Vn){
  const int b = blockIdx.y, s = blockIdx.x, tid = threadIdx.x;
  const float tr = temp[b]; const float tEff = (tr<1e-5f)?1.0f:tr;
  const u32 kbMinKey = ctl[b].kb << BSH;
  const float* Lr = L + (size_t)b*Vn;
  u64* Cr = cand + (size_t)b*CAP;
  const int chunk = (Vn + SL-1)/SL;
  const int i0 = s*chunk, i1 = min(i0+chunk, Vn);
  const int nv = (i1 - i0) / 4;
  const float4* L4 = (const float4*)(Lr + i0);
  const int lane = tid & 63;
  for (int v=tid; v<nv; v+=NT1){
    float4 x = L4[v];
    #pragma unroll
    for (int e=0;e<4;e++){
      float l = (&x.x)[e] / tEff;
      u32 k = key_of(l);
      bool pred = (k >= kbMinKey);
      u64 mk = __ballot(pred);
      if (mk){
        int leader = __ffsll((long long)mk) - 1;
        u32 base = 0;
        if (lane == leader) base = atomicAdd(&ctl[b].cnt0, (u32)__popcll(mk));
        base = __shfl(base, leader, 64);
        if (pred){
          u32 p = base + (u32)__popcll(mk & ((1ull<<lane)-1ull));
          if (p < CAP) Cr[p] = ((u64)k<<32) | (u64)(u32)(i0 + v*4 + e);
        }
      }
    }
  }
  for (int i=i0+nv*4+tid; i<i1; i+=NT1){
    float l = Lr[i]/tEff;
    u32 k = key_of(l);
    if (k >= kbMinKey){
      u32 p = atomicAdd(&ctl[b].cnt0, 1u);
      if (p < CAP) Cr[p] = ((u64)k<<32) | (u64)(u32)i;
    }
  }
}

// k4 v6: 2 histogram levels + 2 tiny mini-loops. 256 threads.
// Level A: 4096-bin count hist over bucket-kb's 19 low bits -> thrKey.
// Level B: 4096-bin mass hist over (key-thrKey)>>sh -> local masked decision.
__global__ __launch_bounds__(NT1) void k4_solve(const float* __restrict__ L,
        const float* __restrict__ temp, const int* __restrict__ top_k,
        const float* __restrict__ top_p, const float* __restrict__ qn,
        const u64* __restrict__ cand, RowCtl* __restrict__ ctl,
        float* __restrict__ out, int Bn, int Vn){
  __shared__ u32 cnt[NBM+1];      // 16.4 KB
  __shared__ u64 mass[NBM+1];     // 32.8 KB
  __shared__ u64 sub[SUB2];
  __shared__ u64 msub[SUB2];
  __shared__ u32 wsc[4];
  __shared__ u64 wsm[4];
  __shared__ int s_cnt, s_bail, s_ga, s_gb;
  __shared__ u32 s_thr;
  __shared__ u64 s_T;
  __shared__ float s_fill[16];
  __shared__ Top5 s_wt5[4];
  __shared__ double s_wr[4];
  __shared__ int s_wri[4], s_wg[4];
  __shared__ u64 s_ms[4], s_pb[4];

  const int b = blockIdx.x, tid = threadIdx.x, lane = tid&63, w = tid>>6;
  const u32 n0raw = ctl[b].cnt0;
  if (n0raw == 0 || n0raw > CAP) return;      // k5 row-fallback
  const int n0 = (int)n0raw;
  const float tr = temp[b]; const float tEff = (tr<1e-5f)?1.0f:tr;
  const float* Lr = L + (size_t)b*Vn;
  const float* Qr = qn + (size_t)b*Vn;
  const u64* Cr = cand + (size_t)b*CAP;
  const u32 kb = ctl[b].kb;
  const u32 rin = ctl[b].rin;
  const u32 mKey = ctl[b].maxKey;
  const float m = key_to_float(mKey);

  // ---- init + load own candidates (coalesced) ----
  for (int i=tid;i<NBM+1;i+=NT1){ cnt[i]=0; mass[i]=0; }
  if (tid==0){ s_cnt=0; s_bail=0; s_T=0; }
  if (tid<16) s_fill[tid] = (tid<Vn) ? Lr[tid] : 0.f;
  u64 pr[EPT4]; u32 kk_[EPT4]; bool vd[EPT4];
  #pragma unroll
  for (int e=0;e<EPT4;e++){
    int p = tid + e*NT1;
    vd[e] = (p < n0);
    pr[e] = vd[e] ? Cr[p] : ~0ull;
    kk_[e] = (u32)(pr[e]>>32);
  }
  __syncthreads();

  // ---- level A: count hist over bucket-kb low 19 bits (bins = bits 18..7) ----
  bool inkb[EPT4];
  #pragma unroll
  for (int e=0;e<EPT4;e++){
    inkb[e] = vd[e] && ((kk_[e]>>BSH) == kb);
    if (inkb[e]) atomicAdd(&cnt[(kk_[e] & 0x7FFFFu) >> 7], 1u);
  }
  scanU32_256(cnt, NBM, wsc);
  for (int g=tid; g<NBM; g+=NT1)
    if (cnt[g] <= rin && rin < cnt[g+1]) s_ga = g;
  __syncthreads();
  const int ga = s_ga;
  const u32 r3 = rin - cnt[ga];
  __syncthreads();            // everyone read cnt[ga] before reuse patterns
  // collect bin-ga elements
  #pragma unroll
  for (int e=0;e<EPT4;e++){
    if (inkb[e] && (int)((kk_[e] & 0x7FFFFu) >> 7) == ga){
      int p = atomicAdd(&s_cnt, 1);
      if (p < SUB2) sub[p] = pr[e]; else s_bail = 1;
    }
  }
  __syncthreads();
  if (s_bail){ if (tid==0) ctl[b].bail = 1; return; }
  const int ncolA = min(s_cnt, SUB2);
  // mini rank loop (ncolA expected 1-4)
  for (int t=tid; t<ncolA; t+=NT1){
    u64 own = sub[t]; u32 rk = 0;
    for (int j=0;j<ncolA;j++) rk += (sub[j] < own);
    if (rk == r3) s_thr = (u32)(own>>32);
  }
  __syncthreads();
  const u32 thrKey = s_thr;   // exact k-th largest key

  // ---- survivor masses + total T ----
  u64 ms_[EPT4];
  u64 locT = 0;
  #pragma unroll
  for (int e=0;e<EPT4;e++){
    ms_[e] = (vd[e] && kk_[e] >= thrKey) ? quantMass(key_to_float(kk_[e]), m) : 0ull;
    locT += ms_[e];
  }
  #pragma unroll
  for (int off=1; off<64; off<<=1) locT += __shfl_xor(locT, off, 64);
  if (lane==0) atomicAdd(&s_T, locT);
  if (tid==0) s_cnt = 0;      // reset for B's collect
  __syncthreads();
  const u64 T = s_T;
  const float cf = 1.0f - top_p[b];           // ref: f32 (1.0 - top_p)
  u64 Q = (u64)((double)cf * (double)T);
  if (Q >= T) Q = T - 1;                      // ref: p_mask[:, -1] = False

  // ---- level B: mass hist over (key - thrKey) >> sh ----
  const u32 span = mKey - thrKey;
  int shb = 0;
  if (span > 4095u){ int hb = 31 - __clz(span); shb = hb - 11; }
  u32 binB[EPT4];
  #pragma unroll
  for (int e=0;e<EPT4;e++){
    binB[e] = ms_[e] ? ((kk_[e] - thrKey) >> shb) : 0u;
    if (ms_[e]) atomicAdd(&mass[binB[e]], ms_[e]);
  }
  scanU64_256(mass, NBM, wsm);
  for (int g=tid; g<NBM; g+=NT1)
    if (mass[g] <= Q && Q < mass[g+1]) s_gb = g;
  __syncthreads();
  const int gb = s_gb;
  const u64 Pgb = mass[gb];
  __syncthreads();
  // collect bin-gb elements (+masses)
  #pragma unroll
  for (int e=0;e<EPT4;e++){
    if (ms_[e] && (int)binB[e] == gb){
      int p = atomicAdd(&s_cnt, 1);
      if (p < SUB2){ sub[p] = pr[e]; msub[p] = ms_[e]; } else s_bail = 1;
    }
  }
  __syncthreads();
  if (s_bail){ if (tid==0) ctl[b].bail = 1; return; }
  const int ncolB = min(s_cnt, SUB2);
  // mini prefix loop: per own in-bin element, mass of in-bin elements before it
  u64 cacc[EPT4];
  bool inb[EPT4];
  #pragma unroll
  for (int e=0;e<EPT4;e++){ cacc[e]=0; inb[e] = (ms_[e] != 0) && ((int)binB[e] == gb); }
  for (int j=0;j<ncolB;j++){
    u64 pj = sub[j]; u64 mj = msub[j];
    #pragma unroll
    for (int e=0;e<EPT4;e++)
      if (inb[e] && pj < pr[e]) cacc[e] += mj;
  }
  // local masked decision
  bool sv[EPT4];
  u64 mm = 0; u64 pb = ~0ull;
  #pragma unroll
  for (int e=0;e<EPT4;e++){
    bool masked = false;
    if (ms_[e]){
      if ((int)binB[e] < gb) masked = true;
      else if ((int)binB[e] == gb && (Pgb + cacc[e] + ms_[e]) <= Q) masked = true;
    }
    sv[e] = (ms_[e] != 0) && !masked;
    if (masked) mm += ms_[e];
    if (sv[e] && pr[e] < pb) pb = pr[e];
  }

  // ---- epilogue: gather q, Gumbel/greedy/top-5, reductions ----
  float qv[EPT4];
  #pragma unroll
  for (int e=0;e<EPT4;e++) qv[e] = sv[e] ? Qr[(u32)pr[e]] : 1.0f;
  Top5 t5; t5_init(t5);
  double br = -1.0; int bri = 0x7FFFFFFF; int gmin = 0x7FFFFFFF;
  #pragma unroll
  for (int e=0;e<EPT4;e++){
    if (sv[e]){
      float l = key_to_float(kk_[e]); int idx = (int)(u32)pr[e];
      double ratio = (double)expf(l - m) / (double)(-logf(qv[e]));
      if (ratio > br || (ratio == br && idx < bri)){ br = ratio; bri = idx; }
      if (kk_[e] == mKey && idx < gmin) gmin = idx;
      t5_insert(t5, l, idx);
    }
  }
  for (int off=1; off<64; off<<=1){
    Top5 o;
    for (int j=0;j<TOPN;j++){ o.v[j]=__shfl_xor(t5.v[j],off,64); o.ix[j]=__shfl_xor(t5.ix[j],off,64); }
    for (int j=0;j<TOPN;j++) t5_insert(t5, o.v[j], o.ix[j]);
    double orr = __shfl_xor(br, off, 64); int ori = __shfl_xor(bri, off, 64);
    if (orr > br || (orr == br && ori < bri)){ br = orr; bri = ori; }
    int og = __shfl_xor(gmin, off, 64); if (og < gmin) gmin = og;
    mm += __shfl_xor(mm, off, 64);
    u64 op = __shfl_xor(pb, off, 64); if (op < pb) pb = op;
  }
  if (lane==0){ s_wt5[w]=t5; s_wr[w]=br; s_wri[w]=bri; s_wg[w]=gmin; s_ms[w]=mm; s_pb[w]=pb; }
  __syncthreads();
  if (tid==0){
    Top5 f = s_wt5[0];
    double fr = s_wr[0]; int fri = s_wri[0]; int fg = s_wg[0];
    u64 fms = s_ms[0]; u64 fpb = s_pb[0];
    for (int wi=1; wi<4; wi++){
      for (int j=0;j<TOPN;j++) t5_insert(f, s_wt5[wi].v[j], s_wt5[wi].ix[j]);
      if (s_wr[wi] > fr || (s_wr[wi]==fr && s_wri[wi]<fri)){ fr=s_wr[wi]; fri=s_wri[wi]; }
      if (s_wg[wi] < fg) fg = s_wg[wi];
      fms += s_ms[wi];
      if (s_pb[wi] < fpb) fpb = s_pb[wi];
    }
    const u64 S2 = T - fms;
    // -inf fill: 5 smallest non-surviving vocab indices live in [0,16) whenever they matter
    int filled = 0;
    for (int i=0; i<16 && i<Vn && filled<TOPN; i++){
      float l = s_fill[i]/tEff;
      u64 pr2 = ((u64)key_of(l)<<32) | (u64)(u32)i;
      if (pr2 < fpb){ t5_insert(f, -INFINITY, i); filled++; }
    }
    double lS = log((double)S2 / SCALE_D);
    int sampled = (tr < 1e-5f) ? fg : fri;
    out[b] = (float)sampled;
    for (int j=0;j<TOPN;j++){
      float lv = f.v[j];
      float lp = (lv == -INFINITY) ? NEG_BIG : (float)((double)lv - (double)m - lS);
      out[Bn + b*TOPN + j] = lp;
      out[Bn + Bn*TOPN + b*TOPN + j] = (float)f.ix[j];
    }
  }
}

// ======================= per-row full fallback (round-2 algorithm, verified) =======================

__device__ void find_cross(const u64* arr, int n, u64 target, int* s_fh, u64* s_fb){
  const int tid = threadIdx.x;
  const int chunk = (n + NT - 1) / NT;
  const int base = tid * chunk;
  for (int j=0;j<chunk;j++){
    int i = base + j;
    if (i < n && arr[i] <= target && target < arr[i+1]){ *s_fh = i; *s_fb = arr[i]; }
  }
  __syncthreads();
}

__device__ void fallback_row(int b, const float* logits, const float* temperature,
                             const int* top_k, const float* top_p, const float* qnoise,
                             float* out, int Bn, int Vn){
  __shared__ u64 s_hist[4097];
  __shared__ u64 s_wsum[NW];
  __shared__ int s_fh;
  __shared__ u64 s_fb;
  __shared__ float s_fm[NW];
  __shared__ float s_m;
  __shared__ int s_lastMax;
  __shared__ int s_eqcnt;
  __shared__ int s_eqlist[1024];
  __shared__ int s_sel;
  __shared__ Top5 s_wt5[NW];
  __shared__ double s_wr[NW];
  __shared__ int s_wri[NW];
  __shared__ int s_wg[NW];
  __shared__ u64 s_ws2[NW];

  const int tid = threadIdx.x, lane = tid & 63, w = tid >> 6;
  const float* L  = logits + (size_t)b * Vn;
  const float* Qr = qnoise + (size_t)b * Vn;
  const float tRaw = temperature[b];
  const float tEff = (tRaw < 1e-5f) ? 1.0f : tRaw;

  for (int i=tid;i<4097;i+=NT) s_hist[i] = 0;
  if (tid==0){ s_lastMax = -1; s_eqcnt = 0; }
  __syncthreads();
  float lm = -INFINITY;
  for (int i=tid;i<Vn;i+=NT){
    float l = L[i] / tEff;
    u32 k = key_of(l);
    atomicAdd(&s_hist[k>>20], 1ull);
    lm = fmaxf(lm, l);
  }
  for (int off=32; off; off>>=1) lm = fmaxf(lm, __shfl_xor(lm, off, 64));
  if (lane==0) s_fm[w] = lm;
  scan_excl(s_hist, 4096, s_wsum);
  if (tid==0){ float mm=-INFINITY; for (int i=0;i<NW;i++) mm=fmaxf(mm,s_fm[i]); s_m=mm; }
  __syncthreads();
  const float m = s_m;

  int kk = top_k[b]; if (kk < 1) kk = 1; if (kk > Vn) kk = Vn;
  u64 r = (u64)(Vn - kk);
  find_cross(s_hist, 4096, r, &s_fh, &s_fb);
  const int kb0 = s_fh; r -= s_fb;
  __syncthreads();

  for (int i=tid;i<4097;i+=NT) s_hist[i]=0;
  __syncthreads();
  for (int i=tid;i<Vn;i+=NT){
    float l = L[i]/tEff; u32 k = key_of(l);
    if ((int)(k>>20) == kb0) atomicAdd(&s_hist[(k>>8)&0xFFFu], 1ull);
  }
  scan_excl(s_hist, 4096, s_wsum);
  find_cross(s_hist, 4096, r, &s_fh, &s_fb);
  const int kb1 = s_fh; r -= s_fb;
  __syncthreads();

  const u32 ktop24 = ((u32)kb0<<12) | (u32)kb1;
  for (int i=tid;i<4097;i+=NT) s_hist[i]=0;
  __syncthreads();
  for (int i=tid;i<Vn;i+=NT){
    float l = L[i]/tEff; u32 k = key_of(l);
    if ((k>>8) == ktop24) atomicAdd(&s_hist[k & 0xFFu], 1ull);
  }
  scan_excl(s_hist, 256, s_wsum);
  find_cross(s_hist, 256, r, &s_fh, &s_fb);
  const u32 thrKey = (ktop24<<8) | (u32)s_fh;
  const float thr = key_to_float(thrKey);
  __syncthreads();

  for (int i=tid;i<4097;i+=NT) s_hist[i]=0;
  __syncthreads();
  for (int i=tid;i<Vn;i+=NT){
    float l = L[i]/tEff;
    if (l >= thr){
      u32 k = key_of(l);
      double sd = exp((double)l - (double)m);
      u64 qv = (u64)(sd * SCALE_D + 0.5);
      atomicAdd(&s_hist[k>>20], qv);
      if (l == m) atomicMax(&s_lastMax, i);
    }
  }
  scan_excl(s_hist, 4096, s_wsum);
  const u64 T = s_hist[4096];
  const float cf = 1.0f - top_p[b];
  const double qtd = (double)cf * (double)T;
  u64 Qfix = (qtd >= (double)T) ? T : (u64)qtd;
  const bool allmask = (Qfix >= T);

  u32 vKey = 0xFFFFFFFFu;
  int idxStar = 0x7FFFFFFF;

  if (!allmask){
    find_cross(s_hist, 4096, Qfix, &s_fh, &s_fb);
    const int g0 = s_fh;
    u64 Qrem = Qfix - s_fb;
    __syncthreads();

    for (int i=tid;i<4097;i+=NT) s_hist[i]=0;
    __syncthreads();
    for (int i=tid;i<Vn;i+=NT){
      float l = L[i]/tEff;
      if (l >= thr){
        u32 k = key_of(l);
        if ((int)(k>>20) == g0){
          double sd = exp((double)l - (double)m);
          atomicAdd(&s_hist[(k>>8)&0xFFFu], (u64)(sd*SCALE_D+0.5));
        }
      }
    }
    scan_excl(s_hist, 4096, s_wsum);
    find_cross(s_hist, 4096, Qrem, &s_fh, &s_fb);
    const int g1 = s_fh; Qrem -= s_fb;
    __syncthreads();

    const u32 ptop24 = ((u32)g0<<12)|(u32)g1;
    for (int i=tid;i<4097;i+=NT) s_hist[i]=0;
    __syncthreads();
    for (int i=tid;i<Vn;i+=NT){
      float l = L[i]/tEff;
      if (l >= thr){
        u32 k = key_of(l);
        if ((k>>8) == ptop24){
          double sd = exp((double)l - (double)m);
          atomicAdd(&s_hist[k & 0xFFu], (u64)(sd*SCALE_D+0.5));
        }
      }
    }
    scan_excl(s_hist, 256, s_wsum);
    find_cross(s_hist, 256, Qrem, &s_fh, &s_fb);
    const int g2 = s_fh;
    const u64 base2 = s_fb;
    const u64 nextPref = s_hist[g2+1];
    Qrem -= base2;
    vKey = (ptop24<<8) | (u32)g2;
    const float vStar = key_to_float(vKey);
    const double sv = exp((double)vStar - (double)m);
    const u64 qstar = (u64)(sv*SCALE_D+0.5);
    u64 nstar = (qstar > 0) ? (nextPref - base2) / qstar : 1ull;
    if (nstar < 1) nstar = 1;
    u64 tmask = (qstar > 0) ? (Qrem / qstar) : 0ull;
    if (tmask >= nstar) tmask = nstar - 1;
    idxStar = -1;
    __syncthreads();
    if (tmask >= 1){
      for (int i=tid;i<Vn;i+=NT){
        float l = L[i]/tEff;
        if (key_of(l) == vKey){
          int p = atomicAdd(&s_eqcnt, 1);
          if (p < 1024) s_eqlist[p] = i;
        }
      }
      __syncthreads();
      if (tid == 0){
        int n_ = s_eqcnt; if (n_ > 1024) n_ = 1024;
        for (int a=1;a<n_;a++){
          int key0 = s_eqlist[a]; int c2=a-1;
          while (c2>=0 && s_eqlist[c2]>key0){ s_eqlist[c2+1]=s_eqlist[c2]; c2--; }
          s_eqlist[c2+1]=key0;
        }
        int ti = (int)tmask - 1;
        if (ti >= n_) ti = n_-1;
        s_sel = s_eqlist[ti];
      }
      __syncthreads();
      idxStar = s_sel;
    }
  }

  const int lastMax = s_lastMax;
  Top5 t5; t5_init(t5);
  u64 s2 = 0;
  double br = -1.0; int bri = 0x7FFFFFFF;
  int gmin = 0x7FFFFFFF;
  for (int i=tid;i<Vn;i+=NT){
    float l = L[i]/tEff;
    u32 k = key_of(l);
    bool surv = (l >= thr) &&
                ((k > vKey) || (k == vKey && i > idxStar) || (i == lastMax));
    float val;
    if (surv){
      double sd = exp((double)l - (double)m);
      s2 += (u64)(sd*SCALE_D+0.5);
      float u = expf(l - m);
      float e = -logf(Qr[i]);
      double ratio = (double)u / (double)e;
      if (ratio > br || (ratio == br && i < bri)){ br = ratio; bri = i; }
      if (l == m && i < gmin) gmin = i;
      val = l;
    } else {
      val = -INFINITY;
    }
    t5_insert(t5, val, i);
  }
  for (int off=1; off<64; off<<=1){
    Top5 o;
    for (int j=0;j<TOPN;j++){ o.v[j]=__shfl_xor(t5.v[j],off,64); o.ix[j]=__shfl_xor(t5.ix[j],off,64); }
    for (int j=0;j<TOPN;j++) t5_insert(t5, o.v[j], o.ix[j]);
    double orr = __shfl_xor(br, off, 64);
    int ori = __shfl_xor(bri, off, 64);
    if (orr > br || (orr == br && ori < bri)){ br = orr; bri = ori; }
    int og = __shfl_xor(gmin, off, 64); if (og < gmin) gmin = og;
    s2 += __shfl_xor(s2, off, 64);
  }
  if (lane == 0){
    s_wt5[w] = t5; s_wr[w]=br; s_wri[w]=bri; s_wg[w]=gmin; s_ws2[w]=s2;
  }
  __syncthreads();
  if (tid == 0){
    Top5 f = s_wt5[0];
    double fr = s_wr[0]; int fri = s_wri[0]; int fg = s_wg[0];
    u64 fs2 = s_ws2[0];
    for (int wi=1; wi<NW; wi++){
      for (int j=0;j<TOPN;j++) t5_insert(f, s_wt5[wi].v[j], s_wt5[wi].ix[j]);
      if (s_wr[wi] > fr || (s_wr[wi]==fr && s_wri[wi]<fri)){ fr=s_wr[wi]; fri=s_wri[wi]; }
      if (s_wg[wi] < fg) fg = s_wg[wi];
      fs2 += s_ws2[wi];
    }
    double S2d = (double)fs2 / SCALE_D;
    double lS = log(S2d);
    int sampled = (tRaw < 1e-5f) ? fg : fri;
    out[b] = (float)sampled;
    for (int j=0;j<TOPN;j++){
      float lv = f.v[j];
      float lp = (lv == -INFINITY) ? NEG_BIG : (float)((double)lv - (double)m - lS);
      out[Bn + b*TOPN + j] = lp;
      out[Bn + Bn*TOPN + b*TOPN + j] = (float)f.ix[j];
    }
  }
}

__global__ __launch_bounds__(NT) void k5_rowfb(const float* __restrict__ logits,
        const float* __restrict__ temperature, const int* __restrict__ top_k,
        const float* __restrict__ top_p, const float* __restrict__ qnoise,
        const RowCtl* __restrict__ ctl, float* __restrict__ out, int Bn, int Vn){
  const int b = blockIdx.x;
  const u32 c = ctl[b].cnt0;
  if (c > 0 && c <= CAP && !ctl[b].bail) return;   // handled by k4
  fallback_row(b, logits, temperature, top_k, top_p, qnoise, out, Bn, Vn);
}

extern "C" __global__ void __launch_bounds__(NT)
sampler_fallback(const float* __restrict__ logits, const float* __restrict__ temperature,
                 const int* __restrict__ top_k, const float* __restrict__ top_p,
                 const float* __restrict__ qnoise, float* __restrict__ out, int Bn, int Vn){
  fallback_row(blockIdx.x, logits, temperature, top_k, top_p, qnoise, out, Bn, Vn);
}

// ======================= launch =======================

extern "C" void kernel_launch(void* const* d_in, const int* in_sizes, int n_in,
                              void* d_out, int out_size, void* d_ws, size_t ws_size,
                              hipStream_t stream)
{
  const float* logits      = (const float*)d_in[0];
  const float* temperature = (const float*)d_in[1];
  const int*   top_k       = (const int*)d_in[2];
  const float* top_p       = (const float*)d_in[3];
  const float* q           = (const float*)d_in[4];
  const int Bn = in_sizes[1];
  const int Vn = in_sizes[0] / Bn;

  const size_t offCand = (size_t)Bn * NB * 4;                 // hist u32
  const size_t offCtl  = offCand + (size_t)Bn * CAP * 8;      // cand u64
  const size_t total   = offCtl + (size_t)Bn * sizeof(RowCtl);

  if (ws_size < total){
    sampler_fallback<<<dim3(Bn), dim3(NT), 0, stream>>>(
        logits, temperature, top_k, top_p, q, (float*)d_out, Bn, Vn);
    return;
  }

  char* wsb = (char*)d_ws;
  u32*    hist = (u32*)wsb;
  u64*    cand = (u64*)(wsb + offCand);
  RowCtl* ctl  = (RowCtl*)(wsb + offCtl);

  k0_zero   <<<dim3(512),     dim3(256), 0, stream>>>(hist, (u32*)ctl, Bn);
  k1_hist   <<<dim3(SL, Bn),  dim3(NT1), 0, stream>>>(logits, temperature, hist, ctl, Bn, Vn);
  k2_kb     <<<dim3(Bn),      dim3(NT),  0, stream>>>(top_k, hist, ctl, Bn, Vn);
  k3_collect<<<dim3(SL, Bn),  dim3(NT1), 0, stream>>>(logits, temperature, cand, ctl, Bn, Vn);
  k4_solve  <<<dim3(Bn),      dim3(NT1), 0, stream>>>(logits, temperature, top_k, top_p, q,
                                                      cand, ctl, (float*)d_out, Bn, Vn);
  k5_rowfb  <<<dim3(Bn),      dim3(NT),  0, stream>>>(logits, temperature, top_k, top_p, q,
                                                      ctl, (float*)d_out, Bn, Vn);
}

// Round 11
// 130.456 us; speedup vs baseline: 1.6604x; 1.0402x over previous
//
#include <hip/hip_runtime.h>
#include <math.h>
#include <float.h>

typedef unsigned long long u64;
typedef unsigned u32;

#define NT 1024        // fallback + k2 block size
#define NW 16
#define NT1 256        // streaming + k4 block size
#define SL 8           // slices per row (k1, k3)
#define NB 8192        // 13-bit value buckets (count hist)
#define BSH 19         // key >> BSH = count bucket
#define NBM 4096       // k4 histogram bins
#define CAP 2048       // candidate capacity per row
#define EPT4 8         // elements per thread in k4
#define SUB2 64        // mini-list capacity
#define TOPN 5
#define SCALE_D 17592186044416.0  // 2^44 fixed-point scale
#define NEG_BIG -3.0e38f          // finite stand-in for -inf on output

// transposed bin address: bin g -> ((g&15)<<8)|(g>>4); thread t's bins t*16+j sit at (j<<8)|t
#define ADDRT(g) ((((g) & 15u) << 8) | ((g) >> 4))

struct RowCtl { u32 kb; u32 cnt0; u32 maxKey; u32 rin; u32 bail; u32 pad[27]; };  // 128 B

__device__ __forceinline__ u32 key_of(float f){
  u32 u = __float_as_uint(f);
  return (u & 0x80000000u) ? ~u : (u | 0x80000000u);
}
__device__ __forceinline__ float key_to_float(u32 k){
  u32 u = (k & 0x80000000u) ? (k & 0x7FFFFFFFu) : ~k;
  return __uint_as_float(u);
}
__device__ __forceinline__ u64 quantMass(float l, float m){
  float ef = expf(l - m);                 // <= 1
  return (u64)((double)ef * SCALE_D + 0.5);
}

struct Top5 { float v[TOPN]; int ix[TOPN]; };
__device__ __forceinline__ void t5_init(Top5& t){
  for (int j=0;j<TOPN;j++){ t.v[j] = -INFINITY; t.ix[j] = 0x7FFFFFFF; }
}
__device__ __forceinline__ void t5_insert(Top5& t, float nv, int ni){
  for (int j=0;j<TOPN;j++){
    if (nv > t.v[j] || (nv == t.v[j] && ni < t.ix[j])){
      for (int s=TOPN-1;s>j;s--){ t.v[s]=t.v[s-1]; t.ix[s]=t.ix[s-1]; }
      t.v[j]=nv; t.ix[j]=ni;
      return;
    }
  }
}

// exclusive prefix sum over arr[0..n), arr[n]=total. 1024 threads (fallback).
__device__ void scan_excl(u64* arr, int n, u64* wsum){
  const int tid = threadIdx.x, lane = tid & 63, w = tid >> 6;
  __syncthreads();
  const int chunk = (n + NT - 1) / NT;
  const int base = tid * chunk;
  u64 local = 0;
  for (int j=0;j<chunk;j++){ int i=base+j; if (i<n) local += arr[i]; }
  u64 inc = local;
  for (int off=1; off<64; off<<=1){
    u64 up = __shfl_up(inc, off, 64);
    if (lane >= off) inc += up;
  }
  if (lane == 63) wsum[w] = inc;
  __syncthreads();
  if (tid == 0){
    u64 acc = 0;
    for (int i=0;i<NW;i++){ u64 v = wsum[i]; wsum[i] = acc; acc += v; }
    arr[n] = acc;
  }
  __syncthreads();
  u64 run = wsum[w] + (inc - local);
  for (int j=0;j<chunk;j++){ int i=base+j; if (i<n){ u64 v=arr[i]; arr[i]=run; run += v; } }
  __syncthreads();
}

// ======================= pipeline kernels =======================

__global__ void k0_zero(u32* __restrict__ hist, u32* __restrict__ ctlw, int Bn){
  size_t n = (size_t)Bn * NB;
  size_t stride = (size_t)gridDim.x * blockDim.x;
  for (size_t i = (size_t)blockIdx.x*blockDim.x + threadIdx.x; i < n; i += stride) hist[i] = 0;
  size_t nc = (size_t)Bn * (sizeof(RowCtl)/4);
  for (size_t i = (size_t)blockIdx.x*blockDim.x + threadIdx.x; i < nc; i += stride) ctlw[i] = 0;
}

__global__ __launch_bounds__(NT1) void k1_hist(const float* __restrict__ L,
        const float* __restrict__ temp, u32* __restrict__ hist, RowCtl* __restrict__ ctl,
        int Bn, int Vn){
  __shared__ u32 lh[NB];
  const int b = blockIdx.y, s = blockIdx.x, tid = threadIdx.x;
  for (int j=tid;j<NB;j+=NT1) lh[j]=0;
  const float tr = temp[b]; const float tEff = (tr < 1e-5f) ? 1.0f : tr;
  const float* Lr = L + (size_t)b*Vn;
  const int chunk = (Vn + SL-1)/SL;
  const int i0 = s*chunk, i1 = min(i0+chunk, Vn);
  __syncthreads();
  const int nv = (i1 - i0) / 4;
  const float4* L4 = (const float4*)(Lr + i0);
  u32 mk = 0;
  for (int v=tid; v<nv; v+=NT1){
    float4 x = L4[v];
    #pragma unroll
    for (int e=0;e<4;e++){
      float l = (&x.x)[e] / tEff;
      u32 k = key_of(l);
      atomicAdd(&lh[k>>BSH], 1u);
      mk = max(mk, k);
    }
  }
  for (int i=i0+nv*4+tid; i<i1; i+=NT1){
    float l = Lr[i]/tEff;
    u32 k = key_of(l);
    atomicAdd(&lh[k>>BSH], 1u);
    mk = max(mk, k);
  }
  for (int off=32; off; off>>=1){ u32 o=__shfl_xor(mk,off,64); mk=max(mk,o); }
  if ((tid&63)==0) atomicMax(&ctl[b].maxKey, mk);
  __syncthreads();
  u32* Hr = hist + (size_t)b*NB;
  for (int j=tid;j<NB;j+=NT1){ u32 c = lh[j]; if (c) atomicAdd(&Hr[j], c); }
}

__global__ __launch_bounds__(NT) void k2_kb(const int* __restrict__ top_k,
        const u32* __restrict__ hist, RowCtl* __restrict__ ctl, int Bn, int Vn){
  __shared__ u32 sh[NB+1];
  __shared__ u32 wsum[NW];
  __shared__ int s_g;
  __shared__ u32 s_base;
  const int b = blockIdx.x, tid = threadIdx.x, lane = tid&63, w = tid>>6;
  const u32* Hr = hist + (size_t)b*NB;
  for (int j=tid;j<NB;j+=NT) sh[j] = Hr[j];
  __syncthreads();
  const int chunk = NB/NT;  // 8
  u32 local=0;
  for (int j=0;j<chunk;j++) local += sh[tid*chunk+j];
  u32 inc = local;
  for (int off=1;off<64;off<<=1){ u32 up=__shfl_up(inc,off,64); if (lane>=off) inc+=up; }
  if (lane==63) wsum[w]=inc;
  __syncthreads();
  if (tid==0){ u32 acc=0; for(int i=0;i<NW;i++){u32 v=wsum[i]; wsum[i]=acc; acc+=v;} sh[NB]=acc; }
  __syncthreads();
  u32 run = wsum[w] + (inc - local);
  for (int j=0;j<chunk;j++){ int i2=tid*chunk+j; u32 v=sh[i2]; sh[i2]=run; run+=v; }
  __syncthreads();
  int kk = top_k[b]; if (kk<1) kk=1; if (kk>Vn) kk=Vn;
  const u32 rank = (u32)(Vn - kk);
  for (int j=tid;j<NB;j+=NT) if (sh[j] <= rank && rank < sh[j+1]){ s_g = j; s_base = sh[j]; }
  __syncthreads();
  if (tid==0){ ctl[b].kb = (u32)s_g; ctl[b].rin = rank - s_base; }
}

__global__ __launch_bounds__(NT1) void k3_collect(const float* __restrict__ L,
        const float* __restrict__ temp, u64* __restrict__ cand, RowCtl* __restrict__ ctl,
        int Bn, int Vn){
  const int b = blockIdx.y, s = blockIdx.x, tid = threadIdx.x;
  const float tr = temp[b]; const float tEff = (tr<1e-5f)?1.0f:tr;
  const u32 kbMinKey = ctl[b].kb << BSH;
  const float* Lr = L + (size_t)b*Vn;
  u64* Cr = cand + (size_t)b*CAP;
  const int chunk = (Vn + SL-1)/SL;
  const int i0 = s*chunk, i1 = min(i0+chunk, Vn);
  const int nv = (i1 - i0) / 4;
  const float4* L4 = (const float4*)(Lr + i0);
  const int lane = tid & 63;
  for (int v=tid; v<nv; v+=NT1){
    float4 x = L4[v];
    #pragma unroll
    for (int e=0;e<4;e++){
      float l = (&x.x)[e] / tEff;
      u32 k = key_of(l);
      bool pred = (k >= kbMinKey);
      u64 mk = __ballot(pred);
      if (mk){
        int leader = __ffsll((long long)mk) - 1;
        u32 base = 0;
        if (lane == leader) base = atomicAdd(&ctl[b].cnt0, (u32)__popcll(mk));
        base = __shfl(base, leader, 64);
        if (pred){
          u32 p = base + (u32)__popcll(mk & ((1ull<<lane)-1ull));
          if (p < CAP) Cr[p] = ((u64)k<<32) | (u64)(u32)(i0 + v*4 + e);
        }
      }
    }
  }
  for (int i=i0+nv*4+tid; i<i1; i+=NT1){
    float l = Lr[i]/tEff;
    u32 k = key_of(l);
    if (k >= kbMinKey){
      u32 p = atomicAdd(&ctl[b].cnt0, 1u);
      if (p < CAP) Cr[p] = ((u64)k<<32) | (u64)(u32)i;
    }
  }
}

// k4 v7: two-level histogram select with TRANSPOSED bins + register scans.
// No scan write-back, no find-cross passes, no LDS bank conflicts on scans.
__global__ __launch_bounds__(NT1) void k4_solve(const float* __restrict__ L,
        const float* __restrict__ temp, const int* __restrict__ top_k,
        const float* __restrict__ top_p, const float* __restrict__ qn,
        const u64* __restrict__ cand, RowCtl* __restrict__ ctl,
        float* __restrict__ out, int Bn, int Vn){
  __shared__ u32 cnt[NBM];        // 16 KB (transposed bins)
  __shared__ u64 mass[NBM];       // 32 KB (transposed bins)
  __shared__ u64 sub[SUB2];
  __shared__ u64 msub[SUB2];
  __shared__ u32 wsc[4];
  __shared__ u64 wsm[4];
  __shared__ int s_cnt, s_bail, s_ga, s_gb;
  __shared__ u32 s_thr, s_r3;
  __shared__ u64 s_Pgb;
  __shared__ float s_fill[16];
  __shared__ Top5 s_wt5[4];
  __shared__ double s_wr[4];
  __shared__ int s_wri[4], s_wg[4];
  __shared__ u64 s_ms[4], s_pb[4];

  const int b = blockIdx.x, tid = threadIdx.x, lane = tid&63, w = tid>>6;
  const u32 n0raw = ctl[b].cnt0;
  if (n0raw == 0 || n0raw > CAP) return;      // k5 row-fallback
  const int n0 = (int)n0raw;
  const float tr = temp[b]; const float tEff = (tr<1e-5f)?1.0f:tr;
  const float* Lr = L + (size_t)b*Vn;
  const float* Qr = qn + (size_t)b*Vn;
  const u64* Cr = cand + (size_t)b*CAP;
  const u32 kb = ctl[b].kb;
  const u32 rin = ctl[b].rin;
  const u32 mKey = ctl[b].maxKey;
  const float m = key_to_float(mKey);

  // ---- init + load own candidates (coalesced) ----
  for (int i=tid;i<NBM;i+=NT1){ cnt[i]=0; mass[i]=0; }
  if (tid==0){ s_cnt=0; s_bail=0; s_ga=0; s_gb=0; s_r3=0; s_Pgb=0; }
  if (tid<16) s_fill[tid] = (tid<Vn) ? Lr[tid] : 0.f;
  u64 pr[EPT4]; u32 kk_[EPT4]; bool vd[EPT4];
  #pragma unroll
  for (int e=0;e<EPT4;e++){
    int p = tid + e*NT1;
    vd[e] = (p < n0);
    pr[e] = vd[e] ? Cr[p] : ~0ull;
    kk_[e] = (u32)(pr[e]>>32);
  }
  __syncthreads();

  // ---- level A: count hist over bucket-kb low 19 bits (bins = bits 18..7) ----
  bool inkb[EPT4]; u32 binA[EPT4];
  #pragma unroll
  for (int e=0;e<EPT4;e++){
    inkb[e] = vd[e] && ((kk_[e]>>BSH) == kb);
    binA[e] = (kk_[e] & 0x7FFFFu) >> 7;
    if (inkb[e]) atomicAdd(&cnt[ADDRT(binA[e])], 1u);
  }
  __syncthreads();
  // register gather (conflict-free) + wave scan + local crossing detection
  {
    u32 c16[16]; u32 lsum = 0;
    #pragma unroll
    for (int j=0;j<16;j++){ c16[j] = cnt[(j<<8)|tid]; lsum += c16[j]; }
    u32 inc = lsum;
    for (int off=1;off<64;off<<=1){ u32 up=__shfl_up(inc,off,64); if (lane>=off) inc+=up; }
    if (lane==63) wsc[w] = inc;
    __syncthreads();
    u32 wb = 0;
    for (int i=0;i<4;i++) if (i<w) wb += wsc[i];
    u32 run = wb + inc - lsum;
    #pragma unroll
    for (int j=0;j<16;j++){
      if (run <= rin && rin < run + c16[j]){ s_ga = tid*16+j; s_r3 = rin - run; }
      run += c16[j];
    }
  }
  __syncthreads();
  const int ga = s_ga;
  const u32 r3 = s_r3;
  // collect bin-ga elements
  #pragma unroll
  for (int e=0;e<EPT4;e++){
    if (inkb[e] && (int)binA[e] == ga){
      int p = atomicAdd(&s_cnt, 1);
      if (p < SUB2) sub[p] = pr[e]; else s_bail = 1;
    }
  }
  __syncthreads();
  if (s_bail){ if (tid==0) ctl[b].bail = 1; return; }
  const int ncolA = min(s_cnt, SUB2);
  // mini rank loop (ncolA expected 1-8)
  for (int t=tid; t<ncolA; t+=NT1){
    u64 own = sub[t]; u32 rk = 0;
    for (int j=0;j<ncolA;j++) rk += (sub[j] < own);
    if (rk == r3) s_thr = (u32)(own>>32);
  }
  __syncthreads();
  const u32 thrKey = s_thr;   // exact k-th largest key

  // ---- survivor masses + level-B mass histogram ----
  u64 ms_[EPT4];
  const u32 span = mKey - thrKey;
  int shb = 0;
  if (span > 4095u){ int hb = 31 - __clz(span); shb = hb - 11; }
  u32 binB[EPT4];
  if (tid==0) s_cnt = 0;      // reset for B's collect (covered by next barrier)
  #pragma unroll
  for (int e=0;e<EPT4;e++){
    ms_[e] = (vd[e] && kk_[e] >= thrKey) ? quantMass(key_to_float(kk_[e]), m) : 0ull;
    binB[e] = ms_[e] ? ((kk_[e] - thrKey) >> shb) : 0u;
    if (ms_[e]) atomicAdd(&mass[ADDRT(binB[e])], ms_[e]);
  }
  __syncthreads();
  // register gather + wave scan; T = total; detect budget crossing locally
  u64 Qq = 0, Tt = 0;
  {
    u64 m16[16]; u64 lsm = 0;
    #pragma unroll
    for (int j=0;j<16;j++){ m16[j] = mass[(j<<8)|tid]; lsm += m16[j]; }
    u64 incm = lsm;
    for (int off=1;off<64;off<<=1){ u64 up=__shfl_up(incm,off,64); if (lane>=off) incm+=up; }
    if (lane==63) wsm[w] = incm;
    __syncthreads();
    u64 wbm = 0, T = 0;
    for (int i=0;i<4;i++){ T += wsm[i]; if (i<w) wbm += wsm[i]; }
    const float cf = 1.0f - top_p[b];         // ref: f32 (1.0 - top_p)
    u64 Q = (u64)((double)cf * (double)T);
    if (Q >= T) Q = T - 1;                    // ref: p_mask[:, -1] = False
    u64 run = wbm + incm - lsm;
    #pragma unroll
    for (int j=0;j<16;j++){
      if (run <= Q && Q < run + m16[j]){ s_gb = tid*16+j; s_Pgb = run; }
      run += m16[j];
    }
    Qq = Q; Tt = T;
  }
  __syncthreads();
  const int gb = s_gb;
  const u64 Pgb = s_Pgb;
  const u64 Q = Qq, T = Tt;
  // collect bin-gb elements (+masses)
  #pragma unroll
  for (int e=0;e<EPT4;e++){
    if (ms_[e] && (int)binB[e] == gb){
      int p = atomicAdd(&s_cnt, 1);
      if (p < SUB2){ sub[p] = pr[e]; msub[p] = ms_[e]; } else s_bail = 1;
    }
  }
  __syncthreads();
  if (s_bail){ if (tid==0) ctl[b].bail = 1; return; }
  const int ncolB = min(s_cnt, SUB2);
  // mini prefix loop: per own in-bin element, mass of in-bin elements before it
  u64 cacc[EPT4];
  bool inb[EPT4];
  #pragma unroll
  for (int e=0;e<EPT4;e++){ cacc[e]=0; inb[e] = (ms_[e] != 0) && ((int)binB[e] == gb); }
  for (int j=0;j<ncolB;j++){
    u64 pj = sub[j]; u64 mj = msub[j];
    #pragma unroll
    for (int e=0;e<EPT4;e++)
      if (inb[e] && pj < pr[e]) cacc[e] += mj;
  }
  // local masked decision
  bool sv[EPT4];
  u64 mm = 0; u64 pb = ~0ull;
  #pragma unroll
  for (int e=0;e<EPT4;e++){
    bool masked = false;
    if (ms_[e]){
      if ((int)binB[e] < gb) masked = true;
      else if ((int)binB[e] == gb && (Pgb + cacc[e] + ms_[e]) <= Q) masked = true;
    }
    sv[e] = (ms_[e] != 0) && !masked;
    if (masked) mm += ms_[e];
    if (sv[e] && pr[e] < pb) pb = pr[e];
  }

  // ---- epilogue: gather q, Gumbel/greedy/top-5, reductions ----
  float qv[EPT4];
  #pragma unroll
  for (int e=0;e<EPT4;e++) qv[e] = sv[e] ? Qr[(u32)pr[e]] : 1.0f;
  Top5 t5; t5_init(t5);
  double br = -1.0; int bri = 0x7FFFFFFF; int gmin = 0x7FFFFFFF;
  #pragma unroll
  for (int e=0;e<EPT4;e++){
    if (sv[e]){
      float l = key_to_float(kk_[e]); int idx = (int)(u32)pr[e];
      double ratio = (double)expf(l - m) / (double)(-logf(qv[e]));
      if (ratio > br || (ratio == br && idx < bri)){ br = ratio; bri = idx; }
      if (kk_[e] == mKey && idx < gmin) gmin = idx;
      t5_insert(t5, l, idx);
    }
  }
  for (int off=1; off<64; off<<=1){
    Top5 o;
    for (int j=0;j<TOPN;j++){ o.v[j]=__shfl_xor(t5.v[j],off,64); o.ix[j]=__shfl_xor(t5.ix[j],off,64); }
    for (int j=0;j<TOPN;j++) t5_insert(t5, o.v[j], o.ix[j]);
    double orr = __shfl_xor(br, off, 64); int ori = __shfl_xor(bri, off, 64);
    if (orr > br || (orr == br && ori < bri)){ br = orr; bri = ori; }
    int og = __shfl_xor(gmin, off, 64); if (og < gmin) gmin = og;
    mm += __shfl_xor(mm, off, 64);
    u64 op = __shfl_xor(pb, off, 64); if (op < pb) pb = op;
  }
  if (lane==0){ s_wt5[w]=t5; s_wr[w]=br; s_wri[w]=bri; s_wg[w]=gmin; s_ms[w]=mm; s_pb[w]=pb; }
  __syncthreads();
  if (tid==0){
    Top5 f = s_wt5[0];
    double fr = s_wr[0]; int fri = s_wri[0]; int fg = s_wg[0];
    u64 fms = s_ms[0]; u64 fpb = s_pb[0];
    for (int wi=1; wi<4; wi++){
      for (int j=0;j<TOPN;j++) t5_insert(f, s_wt5[wi].v[j], s_wt5[wi].ix[j]);
      if (s_wr[wi] > fr || (s_wr[wi]==fr && s_wri[wi]<fri)){ fr=s_wr[wi]; fri=s_wri[wi]; }
      if (s_wg[wi] < fg) fg = s_wg[wi];
      fms += s_ms[wi];
      if (s_pb[wi] < fpb) fpb = s_pb[wi];
    }
    const u64 S2 = T - fms;
    // -inf fill: 5 smallest non-surviving vocab indices live in [0,16) whenever they matter
    int filled = 0;
    for (int i=0; i<16 && i<Vn && filled<TOPN; i++){
      float l = s_fill[i]/tEff;
      u64 pr2 = ((u64)key_of(l)<<32) | (u64)(u32)i;
      if (pr2 < fpb){ t5_insert(f, -INFINITY, i); filled++; }
    }
    double lS = log((double)S2 / SCALE_D);
    int sampled = (tr < 1e-5f) ? fg : fri;
    out[b] = (float)sampled;
    for (int j=0;j<TOPN;j++){
      float lv = f.v[j];
      float lp = (lv == -INFINITY) ? NEG_BIG : (float)((double)lv - (double)m - lS);
      out[Bn + b*TOPN + j] = lp;
      out[Bn + Bn*TOPN + b*TOPN + j] = (float)f.ix[j];
    }
  }
}

// ======================= per-row full fallback (round-2 algorithm, verified) =======================

__device__ void find_cross(const u64* arr, int n, u64 target, int* s_fh, u64* s_fb){
  const int tid = threadIdx.x;
  const int chunk = (n + NT - 1) / NT;
  const int base = tid * chunk;
  for (int j=0;j<chunk;j++){
    int i = base + j;
    if (i < n && arr[i] <= target && target < arr[i+1]){ *s_fh = i; *s_fb = arr[i]; }
  }
  __syncthreads();
}

__device__ void fallback_row(int b, const float* logits, const float* temperature,
                             const int* top_k, const float* top_p, const float* qnoise,
                             float* out, int Bn, int Vn){
  __shared__ u64 s_hist[4097];
  __shared__ u64 s_wsum[NW];
  __shared__ int s_fh;
  __shared__ u64 s_fb;
  __shared__ float s_fm[NW];
  __shared__ float s_m;
  __shared__ int s_lastMax;
  __shared__ int s_eqcnt;
  __shared__ int s_eqlist[1024];
  __shared__ int s_sel;
  __shared__ Top5 s_wt5[NW];
  __shared__ double s_wr[NW];
  __shared__ int s_wri[NW];
  __shared__ int s_wg[NW];
  __shared__ u64 s_ws2[NW];

  const int tid = threadIdx.x, lane = tid & 63, w = tid >> 6;
  const float* L  = logits + (size_t)b * Vn;
  const float* Qr = qnoise + (size_t)b * Vn;
  const float tRaw = temperature[b];
  const float tEff = (tRaw < 1e-5f) ? 1.0f : tRaw;

  for (int i=tid;i<4097;i+=NT) s_hist[i] = 0;
  if (tid==0){ s_lastMax = -1; s_eqcnt = 0; }
  __syncthreads();
  float lm = -INFINITY;
  for (int i=tid;i<Vn;i+=NT){
    float l = L[i] / tEff;
    u32 k = key_of(l);
    atomicAdd(&s_hist[k>>20], 1ull);
    lm = fmaxf(lm, l);
  }
  for (int off=32; off; off>>=1) lm = fmaxf(lm, __shfl_xor(lm, off, 64));
  if (lane==0) s_fm[w] = lm;
  scan_excl(s_hist, 4096, s_wsum);
  if (tid==0){ float mm=-INFINITY; for (int i=0;i<NW;i++) mm=fmaxf(mm,s_fm[i]); s_m=mm; }
  __syncthreads();
  const float m = s_m;

  int kk = top_k[b]; if (kk < 1) kk = 1; if (kk > Vn) kk = Vn;
  u64 r = (u64)(Vn - kk);
  find_cross(s_hist, 4096, r, &s_fh, &s_fb);
  const int kb0 = s_fh; r -= s_fb;
  __syncthreads();

  for (int i=tid;i<4097;i+=NT) s_hist[i]=0;
  __syncthreads();
  for (int i=tid;i<Vn;i+=NT){
    float l = L[i]/tEff; u32 k = key_of(l);
    if ((int)(k>>20) == kb0) atomicAdd(&s_hist[(k>>8)&0xFFFu], 1ull);
  }
  scan_excl(s_hist, 4096, s_wsum);
  find_cross(s_hist, 4096, r, &s_fh, &s_fb);
  const int kb1 = s_fh; r -= s_fb;
  __syncthreads();

  const u32 ktop24 = ((u32)kb0<<12) | (u32)kb1;
  for (int i=tid;i<4097;i+=NT) s_hist[i]=0;
  __syncthreads();
  for (int i=tid;i<Vn;i+=NT){
    float l = L[i]/tEff; u32 k = key_of(l);
    if ((k>>8) == ktop24) atomicAdd(&s_hist[k & 0xFFu], 1ull);
  }
  scan_excl(s_hist, 256, s_wsum);
  find_cross(s_hist, 256, r, &s_fh, &s_fb);
  const u32 thrKey = (ktop24<<8) | (u32)s_fh;
  const float thr = key_to_float(thrKey);
  __syncthreads();

  for (int i=tid;i<4097;i+=NT) s_hist[i]=0;
  __syncthreads();
  for (int i=tid;i<Vn;i+=NT){
    float l = L[i]/tEff;
    if (l >= thr){
      u32 k = key_of(l);
      double sd = exp((double)l - (double)m);
      u64 qv = (u64)(sd * SCALE_D + 0.5);
      atomicAdd(&s_hist[k>>20], qv);
      if (l == m) atomicMax(&s_lastMax, i);
    }
  }
  scan_excl(s_hist, 4096, s_wsum);
  const u64 T = s_hist[4096];
  const float cf = 1.0f - top_p[b];
  const double qtd = (double)cf * (double)T;
  u64 Qfix = (qtd >= (double)T) ? T : (u64)qtd;
  const bool allmask = (Qfix >= T);

  u32 vKey = 0xFFFFFFFFu;
  int idxStar = 0x7FFFFFFF;

  if (!allmask){
    find_cross(s_hist, 4096, Qfix, &s_fh, &s_fb);
    const int g0 = s_fh;
    u64 Qrem = Qfix - s_fb;
    __syncthreads();

    for (int i=tid;i<4097;i+=NT) s_hist[i]=0;
    __syncthreads();
    for (int i=tid;i<Vn;i+=NT){
      float l = L[i]/tEff;
      if (l >= thr){
        u32 k = key_of(l);
        if ((int)(k>>20) == g0){
          double sd = exp((double)l - (double)m);
          atomicAdd(&s_hist[(k>>8)&0xFFFu], (u64)(sd*SCALE_D+0.5));
        }
      }
    }
    scan_excl(s_hist, 4096, s_wsum);
    find_cross(s_hist, 4096, Qrem, &s_fh, &s_fb);
    const int g1 = s_fh; Qrem -= s_fb;
    __syncthreads();

    const u32 ptop24 = ((u32)g0<<12)|(u32)g1;
    for (int i=tid;i<4097;i+=NT) s_hist[i]=0;
    __syncthreads();
    for (int i=tid;i<Vn;i+=NT){
      float l = L[i]/tEff;
      if (l >= thr){
        u32 k = key_of(l);
        if ((k>>8) == ptop24){
          double sd = exp((double)l - (double)m);
          atomicAdd(&s_hist[k & 0xFFu], (u64)(sd*SCALE_D+0.5));
        }
      }
    }
    scan_excl(s_hist, 256, s_wsum);
    find_cross(s_hist, 256, Qrem, &s_fh, &s_fb);
    const int g2 = s_fh;
    const u64 base2 = s_fb;
    const u64 nextPref = s_hist[g2+1];
    Qrem -= base2;
    vKey = (ptop24<<8) | (u32)g2;
    const float vStar = key_to_float(vKey);
    const double sv = exp((double)vStar - (double)m);
    const u64 qstar = (u64)(sv*SCALE_D+0.5);
    u64 nstar = (qstar > 0) ? (nextPref - base2) / qstar : 1ull;
    if (nstar < 1) nstar = 1;
    u64 tmask = (qstar > 0) ? (Qrem / qstar) : 0ull;
    if (tmask >= nstar) tmask = nstar - 1;
    idxStar = -1;
    __syncthreads();
    if (tmask >= 1){
      for (int i=tid;i<Vn;i+=NT){
        float l = L[i]/tEff;
        if (key_of(l) == vKey){
          int p = atomicAdd(&s_eqcnt, 1);
          if (p < 1024) s_eqlist[p] = i;
        }
      }
      __syncthreads();
      if (tid == 0){
        int n_ = s_eqcnt; if (n_ > 1024) n_ = 1024;
        for (int a=1;a<n_;a++){
          int key0 = s_eqlist[a]; int c2=a-1;
          while (c2>=0 && s_eqlist[c2]>key0){ s_eqlist[c2+1]=s_eqlist[c2]; c2--; }
          s_eqlist[c2+1]=key0;
        }
        int ti = (int)tmask - 1;
        if (ti >= n_) ti = n_-1;
        s_sel = s_eqlist[ti];
      }
      __syncthreads();
      idxStar = s_sel;
    }
  }

  const int lastMax = s_lastMax;
  Top5 t5; t5_init(t5);
  u64 s2 = 0;
  double br = -1.0; int bri = 0x7FFFFFFF;
  int gmin = 0x7FFFFFFF;
  for (int i=tid;i<Vn;i+=NT){
    float l = L[i]/tEff;
    u32 k = key_of(l);
    bool surv = (l >= thr) &&
                ((k > vKey) || (k == vKey && i > idxStar) || (i == lastMax));
    float val;
    if (surv){
      double sd = exp((double)l - (double)m);
      s2 += (u64)(sd*SCALE_D+0.5);
      float u = expf(l - m);
      float e = -logf(Qr[i]);
      double ratio = (double)u / (double)e;
      if (ratio > br || (ratio == br && i < bri)){ br = ratio; bri = i; }
      if (l == m && i < gmin) gmin = i;
      val = l;
    } else {
      val = -INFINITY;
    }
    t5_insert(t5, val, i);
  }
  for (int off=1; off<64; off<<=1){
    Top5 o;
    for (int j=0;j<TOPN;j++){ o.v[j]=__shfl_xor(t5.v[j],off,64); o.ix[j]=__shfl_xor(t5.ix[j],off,64); }
    for (int j=0;j<TOPN;j++) t5_insert(t5, o.v[j], o.ix[j]);
    double orr = __shfl_xor(br, off, 64);
    int ori = __shfl_xor(bri, off, 64);
    if (orr > br || (orr == br && ori < bri)){ br = orr; bri = ori; }
    int og = __shfl_xor(gmin, off, 64); if (og < gmin) gmin = og;
    s2 += __shfl_xor(s2, off, 64);
  }
  if (lane == 0){
    s_wt5[w] = t5; s_wr[w]=br; s_wri[w]=bri; s_wg[w]=gmin; s_ws2[w]=s2;
  }
  __syncthreads();
  if (tid == 0){
    Top5 f = s_wt5[0];
    double fr = s_wr[0]; int fri = s_wri[0]; int fg = s_wg[0];
    u64 fs2 = s_ws2[0];
    for (int wi=1; wi<NW; wi++){
      for (int j=0;j<TOPN;j++) t5_insert(f, s_wt5[wi].v[j], s_wt5[wi].ix[j]);
      if (s_wr[wi] > fr || (s_wr[wi]==fr && s_wri[wi]<fri)){ fr=s_wr[wi]; fri=s_wri[wi]; }
      if (s_wg[wi] < fg) fg = s_wg[wi];
      fs2 += s_ws2[wi];
    }
    double S2d = (double)fs2 / SCALE_D;
    double lS = log(S2d);
    int sampled = (tRaw < 1e-5f) ? fg : fri;
    out[b] = (float)sampled;
    for (int j=0;j<TOPN;j++){
      float lv = f.v[j];
      float lp = (lv == -INFINITY) ? NEG_BIG : (float)((double)lv - (double)m - lS);
      out[Bn + b*TOPN + j] = lp;
      out[Bn + Bn*TOPN + b*TOPN + j] = (float)f.ix[j];
    }
  }
}

__global__ __launch_bounds__(NT) void k5_rowfb(const float* __restrict__ logits,
        const float* __restrict__ temperature, const int* __restrict__ top_k,
        const float* __restrict__ top_p, const float* __restrict__ qnoise,
        const RowCtl* __restrict__ ctl, float* __restrict__ out, int Bn, int Vn){
  const int b = blockIdx.x;
  const u32 c = ctl[b].cnt0;
  if (c > 0 && c <= CAP && !ctl[b].bail) return;   // handled by k4
  fallback_row(b, logits, temperature, top_k, top_p, qnoise, out, Bn, Vn);
}

extern "C" __global__ void __launch_bounds__(NT)
sampler_fallback(const float* __restrict__ logits, const float* __restrict__ temperature,
                 const int* __restrict__ top_k, const float* __restrict__ top_p,
                 const float* __restrict__ qnoise, float* __restrict__ out, int Bn, int Vn){
  fallback_row(blockIdx.x, logits, temperature, top_k, top_p, qnoise, out, Bn, Vn);
}

// ======================= launch =======================

extern "C" void kernel_launch(void* const* d_in, const int* in_sizes, int n_in,
                              void* d_out, int out_size, void* d_ws, size_t ws_size,
                              hipStream_t stream)
{
  const float* logits      = (const float*)d_in[0];
  const float* temperature = (const float*)d_in[1];
  const int*   top_k       = (const int*)d_in[2];
  const float* top_p       = (const float*)d_in[3];
  const float* q           = (const float*)d_in[4];
  const int Bn = in_sizes[1];
  const int Vn = in_sizes[0] / Bn;

  const size_t offCand = (size_t)Bn * NB * 4;                 // hist u32
  const size_t offCtl  = offCand + (size_t)Bn * CAP * 8;      // cand u64
  const size_t total   = offCtl + (size_t)Bn * sizeof(RowCtl);

  if (ws_size < total){
    sampler_fallback<<<dim3(Bn), dim3(NT), 0, stream>>>(
        logits, temperature, top_k, top_p, q, (float*)d_out, Bn, Vn);
    return;
  }

  char* wsb = (char*)d_ws;
  u32*    hist = (u32*)wsb;
  u64*    cand = (u64*)(wsb + offCand);
  RowCtl* ctl  = (RowCtl*)(wsb + offCtl);

  k0_zero   <<<dim3(512),     dim3(256), 0, stream>>>(hist, (u32*)ctl, Bn);
  k1_hist   <<<dim3(SL, Bn),  dim3(NT1), 0, stream>>>(logits, temperature, hist, ctl, Bn, Vn);
  k2_kb     <<<dim3(Bn),      dim3(NT),  0, stream>>>(top_k, hist, ctl, Bn, Vn);
  k3_collect<<<dim3(SL, Bn),  dim3(NT1), 0, stream>>>(logits, temperature, cand, ctl, Bn, Vn);
  k4_solve  <<<dim3(Bn),      dim3(NT1), 0, stream>>>(logits, temperature, top_k, top_p, q,
                                                      cand, ctl, (float*)d_out, Bn, Vn);
  k5_rowfb  <<<dim3(Bn),      dim3(NT),  0, stream>>>(logits, temperature, top_k, top_p, q,
                                                      ctl, (float*)d_out, Bn, Vn);
}